// Round 2
// baseline (9439.439 us; speedup 1.0000x reference)
//
#include <hip/hip_runtime.h>
#include <hip/hip_cooperative_groups.h>
#include <cstddef>
#include <cstdint>

namespace cg = cooperative_groups;

namespace {

constexpr int H  = 512;
constexpr int V  = 32000;
constexpr int B  = 64;
constexpr int S  = 64;
constexpr int T  = 32;
constexpr int TQ = 32;

typedef unsigned short ushort_t;
typedef __attribute__((ext_vector_type(8))) short bf16x8;
typedef __attribute__((ext_vector_type(4))) float f32x4;

__device__ __forceinline__ ushort_t f2bf(float f) {
  union { float f; unsigned u; } v; v.f = f;
  return (ushort_t)((v.u + 0x7FFFu + ((v.u >> 16) & 1u)) >> 16);
}

// ---------------------------------------------------------------------------
// Embedding + positional encoding
// ---------------------------------------------------------------------------
__global__ __launch_bounds__(256) void k_embed_facts(const int* __restrict__ ctx,
                                                     const float* __restrict__ emb,
                                                     float* __restrict__ facts_in) {
  const int bs = blockIdx.x;
  const int s  = bs & (S - 1);
  const int t  = threadIdx.x;
  __shared__ int sidx[T];
  if (t < T) sidx[t] = ctx[(size_t)bs * T + t];
  __syncthreads();
  float a0 = 0.f, a1 = 0.f;
  for (int tt = 0; tt < T; ++tt) {
    const int ix = sidx[tt];
    if (ix != 0) {
      const float* e = emb + ((size_t)ix << 9);
      a0 += e[t];
      a1 += e[t + 256];
    }
  }
  const float sf = (float)s * (1.f / 64.f);
  const float c1 = 1.f - sf;
  const float c2 = (1.f - 2.f * sf) * (1.f / 512.f);
  facts_in[((size_t)bs << 9) + t]       = a0 * (c1 - (float)t * c2);
  facts_in[((size_t)bs << 9) + t + 256] = a1 * (c1 - (float)(t + 256) * c2);
}

__global__ __launch_bounds__(256) void k_embed_q(const int* __restrict__ qidx,
                                                 const float* __restrict__ emb,
                                                 float* __restrict__ qe) {
  const int bt = blockIdx.x;
  const int t  = threadIdx.x;
  const int ix = qidx[bt];
  float v0 = 0.f, v1 = 0.f;
  if (ix != 0) {
    const float* e = emb + ((size_t)ix << 9);
    v0 = e[t];
    v1 = e[t + 256];
  }
  qe[((size_t)bt << 9) + t]       = v0;
  qe[((size_t)bt << 9) + t + 256] = v1;
}

__global__ __launch_bounds__(256) void k_transpose512(const float* __restrict__ src,
                                                      float* __restrict__ dst) {
  __shared__ float tile[32][33];
  const int x0 = blockIdx.x * 32, y0 = blockIdx.y * 32;
  for (int i = threadIdx.y; i < 32; i += 8)
    tile[i][threadIdx.x] = src[(size_t)(y0 + i) * H + x0 + threadIdx.x];
  __syncthreads();
  for (int i = threadIdx.y; i < 32; i += 8)
    dst[(size_t)(x0 + i) * H + y0 + threadIdx.x] = tile[threadIdx.x][i];
}

// ---------------------------------------------------------------------------
// f32 GEMM (NT): C = act(A[M,K] @ B[N,K]^T + bias). 64x64 tile.
// ---------------------------------------------------------------------------
template <int ACT>
__global__ __launch_bounds__(256) void k_gemm_nt(const float* __restrict__ A,
                                                 const float* __restrict__ Bm,
                                                 const float* __restrict__ bias,
                                                 float* __restrict__ C,
                                                 int M, int N, int K) {
  __shared__ __align__(16) float As[32][68];
  __shared__ __align__(16) float Bs[32][68];
  const int t  = threadIdx.x;
  const int tx = t & 15, ty = t >> 4;
  const int m0 = blockIdx.y << 6, n0 = blockIdx.x << 6;
  const int lrow = t >> 3;
  const int lcol = (t & 7) << 2;
  float acc[4][4] = {};
  for (int k0 = 0; k0 < K; k0 += 32) {
    const float4 a0 = *(const float4*)(A  + (size_t)(m0 + lrow) * K      + k0 + lcol);
    const float4 a1 = *(const float4*)(A  + (size_t)(m0 + lrow + 32) * K + k0 + lcol);
    const float4 b0 = *(const float4*)(Bm + (size_t)(n0 + lrow) * K      + k0 + lcol);
    const float4 b1 = *(const float4*)(Bm + (size_t)(n0 + lrow + 32) * K + k0 + lcol);
    __syncthreads();
    As[lcol + 0][lrow] = a0.x; As[lcol + 1][lrow] = a0.y; As[lcol + 2][lrow] = a0.z; As[lcol + 3][lrow] = a0.w;
    As[lcol + 0][lrow + 32] = a1.x; As[lcol + 1][lrow + 32] = a1.y; As[lcol + 2][lrow + 32] = a1.z; As[lcol + 3][lrow + 32] = a1.w;
    Bs[lcol + 0][lrow] = b0.x; Bs[lcol + 1][lrow] = b0.y; Bs[lcol + 2][lrow] = b0.z; Bs[lcol + 3][lrow] = b0.w;
    Bs[lcol + 0][lrow + 32] = b1.x; Bs[lcol + 1][lrow + 32] = b1.y; Bs[lcol + 2][lrow + 32] = b1.z; Bs[lcol + 3][lrow + 32] = b1.w;
    __syncthreads();
#pragma unroll 4
    for (int kk = 0; kk < 32; ++kk) {
      float a[4], b[4];
      *(float4*)a = *(const float4*)&As[kk][ty << 2];
      *(float4*)b = *(const float4*)&Bs[kk][tx << 2];
#pragma unroll
      for (int i = 0; i < 4; ++i)
#pragma unroll
        for (int j = 0; j < 4; ++j) acc[i][j] += a[i] * b[j];
    }
  }
#pragma unroll
  for (int i = 0; i < 4; ++i) {
    const int m = m0 + (ty << 2) + i;
#pragma unroll
    for (int j = 0; j < 4; ++j) {
      const int n = n0 + (tx << 2) + j;
      float v = acc[i][j];
      if (bias) v += bias[n];
      if (ACT == 1) v = tanhf(v);
      if (ACT == 2) v = fmaxf(v, 0.f);
      C[(size_t)m * N + n] = v;
    }
  }
}

// ---------------------------------------------------------------------------
// bf16 MFMA GEMM (NT): C f32 = act(A[M,K] @ B[N,K]^T + bias).
// A: bf16 (A_BF16) or f32 (inline-converted). B: f32, inline-converted.
// 64x64 tile, BK=64, 4 waves 2x2, each wave 32x32 (2x2 frags of 16x16x32).
// LDS pad: row stride 72 ushorts -> conflict-free frag reads.
// ---------------------------------------------------------------------------
template <bool A_BF16, int ACT>
__global__ __launch_bounds__(256) void k_gemm_mfma(const void* __restrict__ Av,
                                                   const float* __restrict__ Bm,
                                                   const float* __restrict__ bias,
                                                   float* __restrict__ C,
                                                   int M, int N, int K) {
  __shared__ __align__(16) ushort_t As[64][72];
  __shared__ __align__(16) ushort_t Bs[64][72];
  const int t    = threadIdx.x;
  const int lane = t & 63;
  const int w    = t >> 6;
  const int wr   = w >> 1, wc = w & 1;
  const int m0 = blockIdx.y << 6, n0 = blockIdx.x << 6;
  const int row = t >> 2;          // 0..63 staging row
  const int ch  = t & 3;           // staging chunk (and ch+4)

  f32x4 acc[2][2] = {};

  for (int k0 = 0; k0 < K; k0 += 64) {
    // ---- stage A ----
    if (A_BF16) {
      const ushort_t* A16 = (const ushort_t*)Av;
#pragma unroll
      for (int cc = 0; cc < 2; ++cc) {
        const int c8 = ch + cc * 4;
        const uint4 v = *(const uint4*)(A16 + (size_t)(m0 + row) * K + k0 + c8 * 8);
        *(uint4*)&As[row][c8 * 8] = v;
      }
    } else {
      const float* Af = (const float*)Av;
#pragma unroll
      for (int cc = 0; cc < 2; ++cc) {
        const int c8 = ch + cc * 4;
        const float* src = Af + (size_t)(m0 + row) * K + k0 + c8 * 8;
        const float4 f0 = *(const float4*)src;
        const float4 f1 = *(const float4*)(src + 4);
        uint4 v;
        v.x = (unsigned)f2bf(f0.x) | ((unsigned)f2bf(f0.y) << 16);
        v.y = (unsigned)f2bf(f0.z) | ((unsigned)f2bf(f0.w) << 16);
        v.z = (unsigned)f2bf(f1.x) | ((unsigned)f2bf(f1.y) << 16);
        v.w = (unsigned)f2bf(f1.z) | ((unsigned)f2bf(f1.w) << 16);
        *(uint4*)&As[row][c8 * 8] = v;
      }
    }
    // ---- stage B (always f32 -> bf16) ----
    {
#pragma unroll
      for (int cc = 0; cc < 2; ++cc) {
        const int c8 = ch + cc * 4;
        const float* src = Bm + (size_t)(n0 + row) * K + k0 + c8 * 8;
        const float4 f0 = *(const float4*)src;
        const float4 f1 = *(const float4*)(src + 4);
        uint4 v;
        v.x = (unsigned)f2bf(f0.x) | ((unsigned)f2bf(f0.y) << 16);
        v.y = (unsigned)f2bf(f0.z) | ((unsigned)f2bf(f0.w) << 16);
        v.z = (unsigned)f2bf(f1.x) | ((unsigned)f2bf(f1.y) << 16);
        v.w = (unsigned)f2bf(f1.z) | ((unsigned)f2bf(f1.w) << 16);
        *(uint4*)&Bs[row][c8 * 8] = v;
      }
    }
    __syncthreads();
#pragma unroll
    for (int ks = 0; ks < 2; ++ks) {
      bf16x8 a[2], b[2];
#pragma unroll
      for (int fr = 0; fr < 2; ++fr)
        a[fr] = *(const bf16x8*)&As[wr * 32 + fr * 16 + (lane & 15)][ks * 32 + (lane >> 4) * 8];
#pragma unroll
      for (int fc = 0; fc < 2; ++fc)
        b[fc] = *(const bf16x8*)&Bs[wc * 32 + fc * 16 + (lane & 15)][ks * 32 + (lane >> 4) * 8];
#pragma unroll
      for (int fr = 0; fr < 2; ++fr)
#pragma unroll
        for (int fc = 0; fc < 2; ++fc)
          acc[fr][fc] = __builtin_amdgcn_mfma_f32_16x16x32_bf16(a[fr], b[fc], acc[fr][fc], 0, 0, 0);
    }
    __syncthreads();
  }
  // ---- epilogue: C/D layout col=lane&15, row=(lane>>4)*4+reg ----
#pragma unroll
  for (int fr = 0; fr < 2; ++fr) {
#pragma unroll
    for (int fc = 0; fc < 2; ++fc) {
      const int rbase = m0 + wr * 32 + fr * 16 + ((lane >> 4) << 2);
      const int col   = n0 + wc * 32 + fc * 16 + (lane & 15);
      const float bv  = bias ? bias[col] : 0.f;
#pragma unroll
      for (int j = 0; j < 4; ++j) {
        float v = acc[fr][fc][j] + bv;
        if (ACT == 1) v = tanhf(v);
        if (ACT == 2) v = fmaxf(v, 0.f);
        C[(size_t)(rbase + j) * N + col] = v;
      }
    }
  }
}

// ---------------------------------------------------------------------------
// Cooperative fused GRU scan: all 64 (32 for q) steps in one kernel.
// grid 384 = 3 GRUs x 4 ib (16 items) x 32 jb (16 cols).
// ---------------------------------------------------------------------------
__global__ __launch_bounds__(256) void k_gru_scan(
    const float* Whh_f, const float* bhh_f,
    const float* Whh_b, const float* bhh_b,
    const float* qWhh,  const float* qbhh,
    const float* gx_f, const float* gx_b, const float* gx_q,
    float* Hbuf, float* facts, float* hb_all) {
  cg::grid_group grid = cg::this_grid();
  const int bx  = blockIdx.x;
  const int gru = bx >> 7;
  const int ib  = (bx >> 5) & 3;
  const int jb  = bx & 31;
  const float* Whh; const float* bhh; const float* gx; float* H0; float* H1;
  int seqlen;
  if (gru == 0)      { Whh = Whh_f; bhh = bhh_f; gx = gx_f; H0 = Hbuf;          H1 = Hbuf + 32768;  seqlen = S;  }
  else if (gru == 1) { Whh = Whh_b; bhh = bhh_b; gx = gx_b; H0 = Hbuf + 65536;  H1 = Hbuf + 98304;  seqlen = S;  }
  else               { Whh = qWhh;  bhh = qbhh;  gx = gx_q; H0 = Hbuf + 131072; H1 = Hbuf + 163840; seqlen = TQ; }

  __shared__ __align__(16) float hs[16][516];
  __shared__ float gd[48][17];

  const int t    = threadIdx.x;
  const int item = t & 15;        // phase-1 item
  const int rw   = t >> 4;        // phase-1 local col (0..15)
  const int it2  = t >> 4;        // phase-2 item
  const int cl   = t & 15;        // phase-2 local col
  const int col  = (jb << 4) + cl;
  const int b2   = (ib << 4) + it2;

  const float4* wp[3];
  float bv[3];
#pragma unroll
  for (int rr = 0; rr < 3; ++rr) {
    wp[rr] = (const float4*)(Whh + ((size_t)(rr * 512 + (jb << 4) + rw) << 9));
    bv[rr] = bhh[rr * 512 + col];
  }

  for (int s = 0; s < S; ++s) {
    const bool active = (gru != 2) || (s < TQ);
    if (active) {
      const int xidx = (gru == 1) ? (S - 1 - s) : s;
      const float* Hp = (s & 1) ? H1 : H0;
      float* Hn = (s & 1) ? H0 : H1;
      if (s == 0) {
        for (int i = t; i < 16 * 512; i += 256) hs[i >> 9][i & 511] = 0.f;
      } else {
        for (int i = t; i < 16 * 128; i += 256) {
          const int it = i >> 7, c4 = (i & 127) << 2;
          *(float4*)&hs[it][c4] = *(const float4*)(Hp + ((size_t)((ib << 4) + it) << 9) + c4);
        }
      }
      __syncthreads();
      // phase 1: gate dots (3 rows per thread, same column rw, gates 0..2)
      float acc[3] = {};
#pragma unroll 2
      for (int k4 = 0; k4 < 128; ++k4) {
        const float4 h4 = *(const float4*)&hs[item][k4 << 2];
#pragma unroll
        for (int rr = 0; rr < 3; ++rr) {
          const float4 w4 = wp[rr][k4];
          acc[rr] += w4.x * h4.x + w4.y * h4.y + w4.z * h4.z + w4.w * h4.w;
        }
      }
#pragma unroll
      for (int rr = 0; rr < 3; ++rr) gd[(rr << 4) + rw][item] = acc[rr];
      __syncthreads();
      // phase 2: one output per thread
      const size_t gxrow = ((size_t)b2 * seqlen + xidx) * 1536;
      const float xr = gx[gxrow + col];
      const float xz = gx[gxrow + 512 + col];
      const float xn = gx[gxrow + 1024 + col];
      const float hr = gd[cl][it2]      + bv[0];
      const float hz = gd[16 + cl][it2] + bv[1];
      const float hn = gd[32 + cl][it2] + bv[2];
      const float hp = hs[it2][col];
      const float r = 1.f / (1.f + expf(-(xr + hr)));
      const float z = 1.f / (1.f + expf(-(xz + hz)));
      const float n = tanhf(xn + r * hn);
      const float hnew = (1.f - z) * n + z * hp;
      Hn[((size_t)b2 << 9) + col] = hnew;
      if (gru == 0)      facts[((size_t)(b2 * S + s) << 9) + col]     = hnew;
      else if (gru == 1) hb_all[((size_t)(b2 * S + xidx) << 9) + col] = hnew;
    }
    grid.sync();
  }
}

// Fallback per-step GRU kernel (grid 192), used if cooperative launch fails.
__global__ __launch_bounds__(256) void k_gru_step(
    const float* __restrict__ Whh_f, const float* __restrict__ bhh_f,
    const float* __restrict__ Whh_b, const float* __restrict__ bhh_b,
    const float* __restrict__ qWhh,  const float* __restrict__ qbhh,
    const float* __restrict__ gx_f, const float* __restrict__ gx_b,
    const float* __restrict__ gx_q,
    const float* __restrict__ Hf_prev, float* __restrict__ Hf_next,
    const float* __restrict__ Hb_prev, float* __restrict__ Hb_next,
    const float* __restrict__ Hq_prev, float* __restrict__ Hq_next,
    float* __restrict__ facts, float* __restrict__ hb_all, int s) {
  const int bx  = blockIdx.x;
  const int gru = bx >> 6;
  const int ib  = (bx >> 4) & 3;
  const int jb  = bx & 15;
  if (gru == 2 && s >= TQ) return;
  const float* Whh; const float* bhh; const float* gx; const float* Hp; float* Hn;
  int xidx, seqlen;
  if (gru == 0)      { Whh = Whh_f; bhh = bhh_f; gx = gx_f; Hp = Hf_prev; Hn = Hf_next; xidx = s;         seqlen = S;  }
  else if (gru == 1) { Whh = Whh_b; bhh = bhh_b; gx = gx_b; Hp = Hb_prev; Hn = Hb_next; xidx = S - 1 - s; seqlen = S;  }
  else               { Whh = qWhh;  bhh = qbhh;  gx = gx_q; Hp = Hq_prev; Hn = Hq_next; xidx = s;         seqlen = TQ; }
  __shared__ __align__(16) float hs[16][516];
  __shared__ float gd[96][17];
  const int t = threadIdx.x;
  if (s == 0) {
    for (int i = t; i < 16 * 512; i += 256) hs[i >> 9][i & 511] = 0.f;
  } else {
    for (int i = t; i < 16 * 128; i += 256) {
      const int item = i >> 7, c4 = (i & 127) << 2;
      *(float4*)&hs[item][c4] = *(const float4*)(Hp + ((size_t)(ib * 16 + item) << 9) + c4);
    }
  }
  __syncthreads();
  {
    const int item = t & 15;
    const int rw   = t >> 4;
    const float4* wp[6];
#pragma unroll
    for (int rr = 0; rr < 6; ++rr) {
      const int row_local = rw + (rr << 4);
      const int gate = row_local >> 5;
      const int wrow = (gate << 9) + (jb << 5) + (row_local & 31);
      wp[rr] = (const float4*)(Whh + ((size_t)wrow << 9));
    }
    float acc[6] = {};
#pragma unroll 2
    for (int k4 = 0; k4 < 128; ++k4) {
      const float4 h4 = *(const float4*)&hs[item][k4 << 2];
#pragma unroll
      for (int rr = 0; rr < 6; ++rr) {
        const float4 w4 = wp[rr][k4];
        acc[rr] += w4.x * h4.x + w4.y * h4.y + w4.z * h4.z + w4.w * h4.w;
      }
    }
#pragma unroll
    for (int rr = 0; rr < 6; ++rr) gd[rw + (rr << 4)][item] = acc[rr];
  }
  __syncthreads();
  for (int p = t; p < 512; p += 256) {
    const int it2 = p >> 5;
    const int cl  = p & 31;
    const int col = (jb << 5) + cl;
    const int b   = (ib << 4) + it2;
    const size_t gxrow = ((size_t)b * seqlen + xidx) * 1536;
    const float xr = gx[gxrow + col];
    const float xz = gx[gxrow + 512 + col];
    const float xn = gx[gxrow + 1024 + col];
    const float hr = gd[cl][it2]      + bhh[col];
    const float hz = gd[32 + cl][it2] + bhh[512 + col];
    const float hn = gd[64 + cl][it2] + bhh[1024 + col];
    const float hp = hs[it2][col];
    const float r = 1.f / (1.f + expf(-(xr + hr)));
    const float z = 1.f / (1.f + expf(-(xz + hz)));
    const float n = tanhf(xn + r * hn);
    const float hnew = (1.f - z) * n + z * hp;
    Hn[((size_t)b << 9) + col] = hnew;
    if (gru == 0)      facts[((size_t)(b * S + s) << 9) + col]     = hnew;
    else if (gru == 1) hb_all[((size_t)(b * S + xidx) << 9) + col] = hnew;
  }
}

__global__ __launch_bounds__(256) void k_add(float* __restrict__ a, const float* __restrict__ b) {
  const size_t i = (((size_t)blockIdx.x << 8) + threadIdx.x) << 2;
  float4 x = *(float4*)(a + i);
  const float4 y = *(const float4*)(b + i);
  x.x += y.x; x.y += y.y; x.z += y.z; x.w += y.w;
  *(float4*)(a + i) = x;
}

// z (bf16) = [f*q, f*M, |f-q|, |f-M|]
__global__ __launch_bounds__(256) void k_build_z16(const float* __restrict__ facts,
                                                   const float* __restrict__ q,
                                                   const float* __restrict__ M,
                                                   ushort_t* __restrict__ z) {
  const int bs = blockIdx.x;
  const int b  = bs >> 6;
  const int t  = threadIdx.x;
  const size_t zb = (size_t)bs << 11;
  for (int c = t; c < 512; c += 256) {
    const float f  = facts[((size_t)bs << 9) + c];
    const float qv = q[(b << 9) + c];
    const float mv = M[(b << 9) + c];
    z[zb + c]        = f2bf(f * qv);
    z[zb + 512 + c]  = f2bf(f * mv);
    z[zb + 1024 + c] = f2bf(fabsf(f - qv));
    z[zb + 1536 + c] = f2bf(fabsf(f - mv));
  }
}

__global__ __launch_bounds__(256) void k_score_softmax(const float* __restrict__ g1,
                                                       const float* __restrict__ z2w,
                                                       const float* __restrict__ z2b,
                                                       float* __restrict__ G) {
  const int b = blockIdx.x, t = threadIdx.x;
  const int wave = t >> 6, lane = t & 63;
  __shared__ float sc[64];
  for (int si = 0; si < 16; ++si) {
    const int s = wave * 16 + si;
    const float* row = g1 + ((size_t)(b * S + s) << 9) + lane * 8;
    const float* w   = z2w + lane * 8;
    float p = 0.f;
#pragma unroll
    for (int k = 0; k < 8; ++k) p += row[k] * w[k];
#pragma unroll
    for (int off = 32; off; off >>= 1) p += __shfl_xor(p, off);
    if (lane == 0) sc[s] = p + z2b[0];
  }
  __syncthreads();
  if (wave == 0) {
    const float v = sc[lane];
    float m = v;
#pragma unroll
    for (int off = 32; off; off >>= 1) m = fmaxf(m, __shfl_xor(m, off));
    const float e = expf(v - m);
    float su = e;
#pragma unroll
    for (int off = 32; off; off >>= 1) su += __shfl_xor(su, off);
    G[(b << 6) + lane] = e / su;
  }
}

// ---------------------------------------------------------------------------
// Cooperative fused AGRU scan: 64 steps, weights LDS-resident.
// grid 128 = 4 ib (16 items) x 32 jb (16 cols). LDS ~99KB -> 1 WG/CU.
// ---------------------------------------------------------------------------
__global__ __launch_bounds__(256) void k_agru_scan(
    const float* UrT, const float* UT, const float* fRW, const float* fW,
    const float* br, const float* G, float* C0, float* C1) {
  cg::grid_group grid = cg::this_grid();
  const int ib = blockIdx.x >> 5;
  const int jb = blockIdx.x & 31;
  __shared__ __align__(16) float w0s[16 * 516];
  __shared__ __align__(16) float w1s[16 * 516];
  __shared__ __align__(16) float cs[16][516];
  const int t = threadIdx.x;
  for (int i = t; i < 16 * 128; i += 256) {
    const int c = i >> 7, k4 = (i & 127) << 2;
    *(float4*)&w0s[c * 516 + k4] = *(const float4*)(UrT + (((size_t)((jb << 4) + c)) << 9) + k4);
    *(float4*)&w1s[c * 516 + k4] = *(const float4*)(UT  + (((size_t)((jb << 4) + c)) << 9) + k4);
  }
  const int item = t >> 4, cl = t & 15;
  const int col  = (jb << 4) + cl;
  const int b    = (ib << 4) + item;
  const float brv = br[col];
  const float4* w0 = (const float4*)&w0s[cl * 516];
  const float4* w1 = (const float4*)&w1s[cl * 516];
  for (int s = 0; s < S; ++s) {
    const float* Cp = (s & 1) ? C1 : C0;
    float* Cn = (s & 1) ? C0 : C1;
    if (s == 0) {
      for (int i = t; i < 16 * 512; i += 256) cs[i >> 9][i & 511] = 0.f;
    } else {
      for (int i = t; i < 16 * 128; i += 256) {
        const int it = i >> 7, c4 = (i & 127) << 2;
        *(float4*)&cs[it][c4] = *(const float4*)(Cp + ((size_t)((ib << 4) + it) << 9) + c4);
      }
    }
    __syncthreads();
    float a0 = 0.f, a1 = 0.f;
#pragma unroll 4
    for (int k4 = 0; k4 < 128; ++k4) {
      const float4 c4v = *(const float4*)&cs[item][k4 << 2];
      const float4 wa = w0[k4];
      const float4 wb = w1[k4];
      a0 += wa.x * c4v.x + wa.y * c4v.y + wa.z * c4v.z + wa.w * c4v.w;
      a1 += wb.x * c4v.x + wb.y * c4v.y + wb.z * c4v.z + wb.w * c4v.w;
    }
    const float g   = G[(b << 6) + s];
    const size_t fi = ((size_t)(b * S + s) << 9) + col;
    const float r  = 1.f / (1.f + expf(-(fRW[fi] + a0 + brv)));
    const float ht = tanhf(fW[fi] + r * a1 + brv);
    const float cp = cs[item][col];
    Cn[((size_t)b << 9) + col] = g * ht + (1.f - g) * cp;
    grid.sync();
  }
}

// Fallback per-step AGRU kernel (grid 128).
__global__ __launch_bounds__(256) void k_agru_step(
    const float* __restrict__ UrT, const float* __restrict__ UT,
    const float* __restrict__ fRW, const float* __restrict__ fW,
    const float* __restrict__ br, const float* __restrict__ G,
    const float* __restrict__ Cprev, float* __restrict__ Cnext, int s) {
  const int ib = blockIdx.x >> 5;
  const int jb = blockIdx.x & 31;
  const int t  = threadIdx.x;
  __shared__ __align__(16) float cs[16][516];
  if (s == 0) {
    for (int i = t; i < 16 * 512; i += 256) cs[i >> 9][i & 511] = 0.f;
  } else {
    for (int i = t; i < 16 * 128; i += 256) {
      const int item = i >> 7, c4 = (i & 127) << 2;
      *(float4*)&cs[item][c4] = *(const float4*)(Cprev + ((size_t)(ib * 16 + item) << 9) + c4);
    }
  }
  __syncthreads();
  const int item = t >> 4;
  const int cl   = t & 15;
  const int col  = (jb << 4) + cl;
  const int b    = (ib << 4) + item;
  const float4* w0 = (const float4*)(UrT + ((size_t)col << 9));
  const float4* w1 = (const float4*)(UT  + ((size_t)col << 9));
  float acc0 = 0.f, acc1 = 0.f;
#pragma unroll 4
  for (int k4 = 0; k4 < 128; ++k4) {
    const float4 c4v = *(const float4*)&cs[item][k4 << 2];
    const float4 a = w0[k4];
    const float4 d = w1[k4];
    acc0 += a.x * c4v.x + a.y * c4v.y + a.z * c4v.z + a.w * c4v.w;
    acc1 += d.x * c4v.x + d.y * c4v.y + d.z * c4v.z + d.w * c4v.w;
  }
  const float g   = G[(b << 6) + s];
  const size_t fi = ((size_t)(b * S + s) << 9) + col;
  const float brv = br[col];
  const float r  = 1.f / (1.f + expf(-(fRW[fi] + acc0 + brv)));
  const float ht = tanhf(fW[fi] + r * acc1 + brv);
  const float cp = cs[item][col];
  Cnext[((size_t)b << 9) + col] = g * ht + (1.f - g) * cp;
}

__global__ __launch_bounds__(256) void k_concat3(const float* __restrict__ M,
                                                 const float* __restrict__ C,
                                                 const float* __restrict__ q,
                                                 float* __restrict__ out) {
  const int b = blockIdx.x, t = threadIdx.x;
  for (int c = t; c < 512; c += 256) {
    out[(size_t)b * 1536 + c]        = M[(b << 9) + c];
    out[(size_t)b * 1536 + 512 + c]  = C[(b << 9) + c];
    out[(size_t)b * 1536 + 1024 + c] = q[(b << 9) + c];
  }
}

__global__ __launch_bounds__(256) void k_concat2(const float* __restrict__ M,
                                                 const float* __restrict__ q,
                                                 float* __restrict__ out) {
  const int b = blockIdx.x, t = threadIdx.x;
  for (int c = t; c < 512; c += 256) {
    out[(size_t)b * 1024 + c]       = M[(b << 9) + c];
    out[(size_t)b * 1024 + 512 + c] = q[(b << 9) + c];
  }
}

}  // namespace

extern "C" void kernel_launch(void* const* d_in, const int* in_sizes, int n_in,
                              void* d_out, int out_size, void* d_ws, size_t ws_size,
                              hipStream_t stream) {
  const int*   contexts  = (const int*)d_in[0];
  const int*   questions = (const int*)d_in[1];
  const float* emb   = (const float*)d_in[2];
  const float* Wih_f = (const float*)d_in[3];
  const float* Whh_f = (const float*)d_in[4];
  const float* bih_f = (const float*)d_in[5];
  const float* bhh_f = (const float*)d_in[6];
  const float* Wih_b = (const float*)d_in[7];
  const float* Whh_b = (const float*)d_in[8];
  const float* bih_b = (const float*)d_in[9];
  const float* bhh_b = (const float*)d_in[10];
  const float* qWih  = (const float*)d_in[11];
  const float* qWhh  = (const float*)d_in[12];
  const float* qbih  = (const float*)d_in[13];
  const float* qbhh  = (const float*)d_in[14];
  const float* Wr    = (const float*)d_in[15];
  const float* Ur    = (const float*)d_in[16];
  const float* br    = (const float*)d_in[17];
  const float* Wm    = (const float*)d_in[18];
  const float* Um    = (const float*)d_in[19];
  const float* z1_w  = (const float*)d_in[20];
  const float* z1_b  = (const float*)d_in[21];
  const float* z2_w  = (const float*)d_in[22];
  const float* z2_b  = (const float*)d_in[23];
  const float* nm_w  = (const float*)d_in[24];
  const float* nm_b  = (const float*)d_in[25];
  const float* ans_w = (const float*)d_in[26];
  const float* ans_b = (const float*)d_in[27];
  (void)in_sizes; (void)n_in; (void)out_size; (void)ws_size;

  float* ws = (float*)d_ws;
  float* WrT      = ws + 0;          // 262144
  float* UrT      = ws + 262144;     // 262144
  float* WT       = ws + 524288;     // 262144
  float* UT       = ws + 786432;     // 262144
  float* facts_in = ws + 1048576;    // 2097152  (reused as fRW)
  float* qe       = ws + 3145728;    // 1048576
  float* gx_f     = ws + 4194304;    // 6291456  (reused as z bf16)
  float* gx_b     = ws + 10485760;   // 6291456
  float* gx_q     = ws + 16777216;   // 3145728  (reused as g1)
  float* facts    = ws + 19922944;   // 2097152
  float* hb       = ws + 22020096;   // 2097152  (reused as fW)
  float* Hbuf     = ws + 24117248;   // 196608
  float* C0       = ws + 24313856;   // 32768
  float* C1       = ws + 24346624;   // 32768
  float* M0       = ws + 24379392;   // 32768
  float* M1       = ws + 24412160;   // 32768
  float* MCq      = ws + 24444928;   // 98304
  float* Mq       = ws + 24543232;   // 65536
  float* Gm       = ws + 24608768;   // 4096
  ushort_t* zb16 = (ushort_t*)gx_f;  // 4096x2048 bf16 = 16MB (gx_f dead)
  float* g1  = gx_q;
  float* fRW = facts_in;
  float* fW  = hb;
  float* preds = (float*)d_out;

  float* Hf[2]  = {Hbuf,          Hbuf + 32768};
  float* Hb2[2] = {Hbuf + 65536,  Hbuf + 98304};
  float* Hq[2]  = {Hbuf + 131072, Hbuf + 163840};
  float* q = Hq[0];
  float* Cb[2] = {C0, C1};

  // ---- stage A: embeddings + weight transposes ----
  k_embed_facts<<<B * S, 256, 0, stream>>>(contexts, emb, facts_in);
  k_embed_q<<<B * TQ, 256, 0, stream>>>(questions, emb, qe);
  dim3 tb(32, 8);
  k_transpose512<<<dim3(16, 16), tb, 0, stream>>>(Wr, WrT);
  k_transpose512<<<dim3(16, 16), tb, 0, stream>>>(Ur, UrT);
  k_transpose512<<<dim3(16, 16), tb, 0, stream>>>(Wm, WT);
  k_transpose512<<<dim3(16, 16), tb, 0, stream>>>(Um, UT);

  // ---- stage B: input-side gate GEMMs (f32, feeds recurrence) ----
  k_gemm_nt<0><<<dim3(24, 64), 256, 0, stream>>>(facts_in, Wih_f, bih_f, gx_f, 4096, 1536, 512);
  k_gemm_nt<0><<<dim3(24, 64), 256, 0, stream>>>(facts_in, Wih_b, bih_b, gx_b, 4096, 1536, 512);
  k_gemm_nt<0><<<dim3(24, 32), 256, 0, stream>>>(qe, qWih, qbih, gx_q, 2048, 1536, 512);

  // ---- stage C: fused GRU scan (cooperative; fallback per-step) ----
  {
    void* args[] = { (void*)&Whh_f, (void*)&bhh_f, (void*)&Whh_b, (void*)&bhh_b,
                     (void*)&qWhh, (void*)&qbhh, (void*)&gx_f, (void*)&gx_b,
                     (void*)&gx_q, (void*)&Hbuf, (void*)&facts, (void*)&hb };
    hipError_t e = hipLaunchCooperativeKernel(reinterpret_cast<void*>(k_gru_scan),
                                              dim3(384), dim3(256), args, 0, stream);
    if (e != hipSuccess) {
      for (int s = 0; s < S; ++s)
        k_gru_step<<<192, 256, 0, stream>>>(Whh_f, bhh_f, Whh_b, bhh_b, qWhh, qbhh,
                                            gx_f, gx_b, gx_q,
                                            Hf[s & 1], Hf[(s + 1) & 1],
                                            Hb2[s & 1], Hb2[(s + 1) & 1],
                                            Hq[s & 1], Hq[(s + 1) & 1],
                                            facts, hb, s);
    }
  }
  k_add<<<2048, 256, 0, stream>>>(facts, hb);

  // ---- stage D: hop-invariant precomputes (f32, feeds recurrence) ----
  k_gemm_nt<0><<<dim3(8, 64), 256, 0, stream>>>(facts, WrT, nullptr, fRW, 4096, 512, 512);
  k_gemm_nt<0><<<dim3(8, 64), 256, 0, stream>>>(facts, WT,  nullptr, fW,  4096, 512, 512);

  // ---- stage E: episodic memory hops ----
  const float* Mcur = q;
  for (int h = 0; h < 3; ++h) {
    k_build_z16<<<B * S, 256, 0, stream>>>(facts, q, Mcur, zb16);
    k_gemm_mfma<true, 1><<<dim3(8, 64), 256, 0, stream>>>(zb16, z1_w, z1_b, g1, 4096, 512, 2048);
    k_score_softmax<<<B, 256, 0, stream>>>(g1, z2_w, z2_b, Gm);
    {
      void* aargs[] = { (void*)&UrT, (void*)&UT, (void*)&fRW, (void*)&fW,
                        (void*)&br, (void*)&Gm, (void*)&C0, (void*)&C1 };
      hipError_t e = hipLaunchCooperativeKernel(reinterpret_cast<void*>(k_agru_scan),
                                                dim3(128), dim3(256), aargs, 0, stream);
      if (e != hipSuccess) {
        for (int s = 0; s < S; ++s)
          k_agru_step<<<128, 256, 0, stream>>>(UrT, UT, fRW, fW, br, Gm,
                                               Cb[s & 1], Cb[(s + 1) & 1], s);
      }
    }
    k_concat3<<<B, 256, 0, stream>>>(Mcur, C0, q, MCq);
    float* Mnext = (h & 1) ? M1 : M0;
    k_gemm_nt<2><<<dim3(8, 1), 256, 0, stream>>>(MCq, nm_w, nm_b, Mnext, 64, 512, 1536);
    Mcur = Mnext;
  }

  // ---- stage F: answer projection (bf16 MFMA, inline-converted) ----
  k_concat2<<<B, 256, 0, stream>>>(Mcur, q, Mq);
  k_gemm_mfma<false, 0><<<dim3(500, 1), 256, 0, stream>>>(Mq, ans_w, ans_b, preds, 64, 32000, 1024);
}

// Round 4
// 7306.444 us; speedup vs baseline: 1.2919x; 1.2919x over previous
//
#include <hip/hip_runtime.h>
#include <cstddef>
#include <cstdint>

namespace {

constexpr int H  = 512;
constexpr int V  = 32000;
constexpr int B  = 64;
constexpr int S  = 64;
constexpr int T  = 32;
constexpr int TQ = 32;

// LDS row stride for scan kernels: 520 floats -> start bank = row*2 mod 32,
// 2-way max aliasing (free, m136). 516 gave 4-way (1.58x).
constexpr int WST = 520;

typedef unsigned short ushort_t;
typedef __attribute__((ext_vector_type(8))) short bf16x8;
typedef __attribute__((ext_vector_type(4))) float f32x4;

__device__ __forceinline__ ushort_t f2bf(float f) {
  union { float f; unsigned u; } v; v.f = f;
  return (ushort_t)((v.u + 0x7FFFu + ((v.u >> 16) & 1u)) >> 16);
}

__device__ __forceinline__ float sigm(float x) { return 1.f / (1.f + expf(-x)); }

// Group-local monotonic barrier. cell: one u32 counter (own 256B region).
// All 32 WGs of a group arrive; spin until counter >= target.
__device__ __forceinline__ void group_barrier(unsigned* cell, unsigned target) {
  __syncthreads();
  if (threadIdx.x == 0) {
    __threadfence();   // release: L2 writeback so other XCDs see our stores
    __hip_atomic_fetch_add(cell, 1u, __ATOMIC_ACQ_REL, __HIP_MEMORY_SCOPE_AGENT);
    unsigned v;
    do {
      v = __hip_atomic_load(cell, __ATOMIC_RELAXED, __HIP_MEMORY_SCOPE_AGENT);
      if (v < target) __builtin_amdgcn_s_sleep(8);
    } while (v < target);
    __threadfence();   // acquire: invalidate stale lines before next reads
  }
  __syncthreads();
}

// ---------------------------------------------------------------------------
// Embedding + positional encoding
// ---------------------------------------------------------------------------
__global__ __launch_bounds__(256) void k_embed_facts(const int* __restrict__ ctx,
                                                     const float* __restrict__ emb,
                                                     float* __restrict__ facts_in) {
  const int bs = blockIdx.x;
  const int s  = bs & (S - 1);
  const int t  = threadIdx.x;
  __shared__ int sidx[T];
  if (t < T) sidx[t] = ctx[(size_t)bs * T + t];
  __syncthreads();
  float a0 = 0.f, a1 = 0.f;
  for (int tt = 0; tt < T; ++tt) {
    const int ix = sidx[tt];
    if (ix != 0) {
      const float* e = emb + ((size_t)ix << 9);
      a0 += e[t];
      a1 += e[t + 256];
    }
  }
  const float sf = (float)s * (1.f / 64.f);
  const float c1 = 1.f - sf;
  const float c2 = (1.f - 2.f * sf) * (1.f / 512.f);
  facts_in[((size_t)bs << 9) + t]       = a0 * (c1 - (float)t * c2);
  facts_in[((size_t)bs << 9) + t + 256] = a1 * (c1 - (float)(t + 256) * c2);
}

__global__ __launch_bounds__(256) void k_embed_q(const int* __restrict__ qidx,
                                                 const float* __restrict__ emb,
                                                 float* __restrict__ qe) {
  const int bt = blockIdx.x;
  const int t  = threadIdx.x;
  const int ix = qidx[bt];
  float v0 = 0.f, v1 = 0.f;
  if (ix != 0) {
    const float* e = emb + ((size_t)ix << 9);
    v0 = e[t];
    v1 = e[t + 256];
  }
  qe[((size_t)bt << 9) + t]       = v0;
  qe[((size_t)bt << 9) + t + 256] = v1;
}

__global__ __launch_bounds__(256) void k_transpose512(const float* __restrict__ src,
                                                      float* __restrict__ dst) {
  __shared__ float tile[32][33];
  const int x0 = blockIdx.x * 32, y0 = blockIdx.y * 32;
  for (int i = threadIdx.y; i < 32; i += 8)
    tile[i][threadIdx.x] = src[(size_t)(y0 + i) * H + x0 + threadIdx.x];
  __syncthreads();
  for (int i = threadIdx.y; i < 32; i += 8)
    dst[(size_t)(x0 + i) * H + y0 + threadIdx.x] = tile[threadIdx.x][i];
}

// ---------------------------------------------------------------------------
// f32 GEMM (NT): C = act(A[M,K] @ B[N,K]^T + bias). 64x64 tile.
// ---------------------------------------------------------------------------
template <int ACT>
__global__ __launch_bounds__(256) void k_gemm_nt(const float* __restrict__ A,
                                                 const float* __restrict__ Bm,
                                                 const float* __restrict__ bias,
                                                 float* __restrict__ C,
                                                 int M, int N, int K) {
  __shared__ __align__(16) float As[32][68];
  __shared__ __align__(16) float Bs[32][68];
  const int t  = threadIdx.x;
  const int tx = t & 15, ty = t >> 4;
  const int m0 = blockIdx.y << 6, n0 = blockIdx.x << 6;
  const int lrow = t >> 3;
  const int lcol = (t & 7) << 2;
  float acc[4][4] = {};
  for (int k0 = 0; k0 < K; k0 += 32) {
    const float4 a0 = *(const float4*)(A  + (size_t)(m0 + lrow) * K      + k0 + lcol);
    const float4 a1 = *(const float4*)(A  + (size_t)(m0 + lrow + 32) * K + k0 + lcol);
    const float4 b0 = *(const float4*)(Bm + (size_t)(n0 + lrow) * K      + k0 + lcol);
    const float4 b1 = *(const float4*)(Bm + (size_t)(n0 + lrow + 32) * K + k0 + lcol);
    __syncthreads();
    As[lcol + 0][lrow] = a0.x; As[lcol + 1][lrow] = a0.y; As[lcol + 2][lrow] = a0.z; As[lcol + 3][lrow] = a0.w;
    As[lcol + 0][lrow + 32] = a1.x; As[lcol + 1][lrow + 32] = a1.y; As[lcol + 2][lrow + 32] = a1.z; As[lcol + 3][lrow + 32] = a1.w;
    Bs[lcol + 0][lrow] = b0.x; Bs[lcol + 1][lrow] = b0.y; Bs[lcol + 2][lrow] = b0.z; Bs[lcol + 3][lrow] = b0.w;
    Bs[lcol + 0][lrow + 32] = b1.x; Bs[lcol + 1][lrow + 32] = b1.y; Bs[lcol + 2][lrow + 32] = b1.z; Bs[lcol + 3][lrow + 32] = b1.w;
    __syncthreads();
#pragma unroll 4
    for (int kk = 0; kk < 32; ++kk) {
      float a[4], b[4];
      *(float4*)a = *(const float4*)&As[kk][ty << 2];
      *(float4*)b = *(const float4*)&Bs[kk][tx << 2];
#pragma unroll
      for (int i = 0; i < 4; ++i)
#pragma unroll
        for (int j = 0; j < 4; ++j) acc[i][j] += a[i] * b[j];
    }
  }
#pragma unroll
  for (int i = 0; i < 4; ++i) {
    const int m = m0 + (ty << 2) + i;
#pragma unroll
    for (int j = 0; j < 4; ++j) {
      const int n = n0 + (tx << 2) + j;
      float v = acc[i][j];
      if (bias) v += bias[n];
      if (ACT == 1) v = tanhf(v);
      if (ACT == 2) v = fmaxf(v, 0.f);
      C[(size_t)m * N + n] = v;
    }
  }
}

// ---------------------------------------------------------------------------
// bf16 MFMA GEMM (NT), as validated in round 2.
// ---------------------------------------------------------------------------
template <bool A_BF16, int ACT>
__global__ __launch_bounds__(256) void k_gemm_mfma(const void* __restrict__ Av,
                                                   const float* __restrict__ Bm,
                                                   const float* __restrict__ bias,
                                                   float* __restrict__ C,
                                                   int M, int N, int K) {
  __shared__ __align__(16) ushort_t As[64][72];
  __shared__ __align__(16) ushort_t Bs[64][72];
  const int t    = threadIdx.x;
  const int lane = t & 63;
  const int w    = t >> 6;
  const int wr   = w >> 1, wc = w & 1;
  const int m0 = blockIdx.y << 6, n0 = blockIdx.x << 6;
  const int row = t >> 2;
  const int ch  = t & 3;

  f32x4 acc[2][2] = {};

  for (int k0 = 0; k0 < K; k0 += 64) {
    if (A_BF16) {
      const ushort_t* A16 = (const ushort_t*)Av;
#pragma unroll
      for (int cc = 0; cc < 2; ++cc) {
        const int c8 = ch + cc * 4;
        const uint4 v = *(const uint4*)(A16 + (size_t)(m0 + row) * K + k0 + c8 * 8);
        *(uint4*)&As[row][c8 * 8] = v;
      }
    } else {
      const float* Af = (const float*)Av;
#pragma unroll
      for (int cc = 0; cc < 2; ++cc) {
        const int c8 = ch + cc * 4;
        const float* src = Af + (size_t)(m0 + row) * K + k0 + c8 * 8;
        const float4 f0 = *(const float4*)src;
        const float4 f1 = *(const float4*)(src + 4);
        uint4 v;
        v.x = (unsigned)f2bf(f0.x) | ((unsigned)f2bf(f0.y) << 16);
        v.y = (unsigned)f2bf(f0.z) | ((unsigned)f2bf(f0.w) << 16);
        v.z = (unsigned)f2bf(f1.x) | ((unsigned)f2bf(f1.y) << 16);
        v.w = (unsigned)f2bf(f1.z) | ((unsigned)f2bf(f1.w) << 16);
        *(uint4*)&As[row][c8 * 8] = v;
      }
    }
    {
#pragma unroll
      for (int cc = 0; cc < 2; ++cc) {
        const int c8 = ch + cc * 4;
        const float* src = Bm + (size_t)(n0 + row) * K + k0 + c8 * 8;
        const float4 f0 = *(const float4*)src;
        const float4 f1 = *(const float4*)(src + 4);
        uint4 v;
        v.x = (unsigned)f2bf(f0.x) | ((unsigned)f2bf(f0.y) << 16);
        v.y = (unsigned)f2bf(f0.z) | ((unsigned)f2bf(f0.w) << 16);
        v.z = (unsigned)f2bf(f1.x) | ((unsigned)f2bf(f1.y) << 16);
        v.w = (unsigned)f2bf(f1.z) | ((unsigned)f2bf(f1.w) << 16);
        *(uint4*)&Bs[row][c8 * 8] = v;
      }
    }
    __syncthreads();
#pragma unroll
    for (int ks = 0; ks < 2; ++ks) {
      bf16x8 a[2], b[2];
#pragma unroll
      for (int fr = 0; fr < 2; ++fr)
        a[fr] = *(const bf16x8*)&As[wr * 32 + fr * 16 + (lane & 15)][ks * 32 + (lane >> 4) * 8];
#pragma unroll
      for (int fc = 0; fc < 2; ++fc)
        b[fc] = *(const bf16x8*)&Bs[wc * 32 + fc * 16 + (lane & 15)][ks * 32 + (lane >> 4) * 8];
#pragma unroll
      for (int fr = 0; fr < 2; ++fr)
#pragma unroll
        for (int fc = 0; fc < 2; ++fc)
          acc[fr][fc] = __builtin_amdgcn_mfma_f32_16x16x32_bf16(a[fr], b[fc], acc[fr][fc], 0, 0, 0);
    }
    __syncthreads();
  }
#pragma unroll
  for (int fr = 0; fr < 2; ++fr) {
#pragma unroll
    for (int fc = 0; fc < 2; ++fc) {
      const int rbase = m0 + wr * 32 + fr * 16 + ((lane >> 4) << 2);
      const int col   = n0 + wc * 32 + fc * 16 + (lane & 15);
      const float bv  = bias ? bias[col] : 0.f;
#pragma unroll
      for (int j = 0; j < 4; ++j) {
        float v = acc[fr][fc][j] + bv;
        if (ACT == 1) v = tanhf(v);
        if (ACT == 2) v = fmaxf(v, 0.f);
        C[(size_t)(rbase + j) * N + col] = v;
      }
    }
  }
}

// ---------------------------------------------------------------------------
// Persistent GRU scan, one GRU per launch. 256 WGs = 8 ib (8 items) x 32 jb
// (16 cols). Weights LDS-resident (staged once); group-local barriers over
// the 32 jb-WGs of each ib. Thread = (item, col, k-half) + shfl combine.
// ---------------------------------------------------------------------------
__global__ __launch_bounds__(256) void k_gru_scan3(
    const float* __restrict__ Whh, const float* __restrict__ bhh,
    const float* __restrict__ gx, float* __restrict__ H0, float* __restrict__ H1,
    float* __restrict__ out_seq, int seqlen, int rev,
    unsigned* __restrict__ bar) {
  const int ib = blockIdx.x >> 5;
  const int jb = blockIdx.x & 31;
  __shared__ __align__(16) float wlds[48 * WST];
  __shared__ __align__(16) float hs[8 * WST];
  const int t = threadIdx.x;

  // stage weight slice once: rows g*16+c <- Whh[g*512 + jb*16 + c][:]
  for (int i = t; i < 48 * 128; i += 256) {
    const int row = i >> 7, k4 = (i & 127) << 2;
    const int g = row >> 4, c = row & 15;
    *(float4*)&wlds[row * WST + k4] =
        *(const float4*)(Whh + ((size_t)(g * 512 + (jb << 4) + c) << 9) + k4);
  }

  const int kh   = t & 1;
  const int cl   = (t >> 1) & 15;
  const int item = t >> 5;
  const int col  = (jb << 4) + cl;
  const int b    = (ib << 3) + item;
  const float bv0 = bhh[col];
  const float bv1 = bhh[512 + col];
  const float bv2 = bhh[1024 + col];
  const float4* w0 = (const float4*)&wlds[(cl) * WST + (kh << 8)];
  const float4* w1 = (const float4*)&wlds[(16 + cl) * WST + (kh << 8)];
  const float4* w2 = (const float4*)&wlds[(32 + cl) * WST + (kh << 8)];
  const float4* hsp = (const float4*)&hs[item * WST + (kh << 8)];
  unsigned* cell = bar + ib * 64;
  unsigned tgt = 0;

  for (int s = 0; s < seqlen; ++s) {
    // stage h state for this step
    if (s == 0) {
      for (int i = t; i < 8 * 128; i += 256) {
        const int it = i >> 7, k4 = (i & 127) << 2;
        *(float4*)&hs[it * WST + k4] = float4{0.f, 0.f, 0.f, 0.f};
      }
    } else {
      const float* Hp = (s & 1) ? H1 : H0;
      for (int i = t; i < 8 * 128; i += 256) {
        const int it = i >> 7, k4 = (i & 127) << 2;
        *(float4*)&hs[it * WST + k4] =
            *(const float4*)(Hp + ((size_t)((ib << 3) + it) << 9) + k4);
      }
    }
    __syncthreads();

    const int xidx = rev ? (seqlen - 1 - s) : s;
    // issue gx loads early (kh==0 lanes), latency hides under the dot
    float xr = 0.f, xz = 0.f, xn = 0.f;
    if (kh == 0) {
      const size_t gxrow = ((size_t)b * seqlen + xidx) * 1536;
      xr = gx[gxrow + col];
      xz = gx[gxrow + 512 + col];
      xn = gx[gxrow + 1024 + col];
    }

    float a0 = 0.f, a1 = 0.f, a2 = 0.f;
#pragma unroll 4
    for (int k4 = 0; k4 < 64; ++k4) {
      const float4 h4 = hsp[k4];
      const float4 x0 = w0[k4];
      const float4 x1 = w1[k4];
      const float4 x2 = w2[k4];
      a0 += x0.x * h4.x + x0.y * h4.y + x0.z * h4.z + x0.w * h4.w;
      a1 += x1.x * h4.x + x1.y * h4.y + x1.z * h4.z + x1.w * h4.w;
      a2 += x2.x * h4.x + x2.y * h4.y + x2.z * h4.z + x2.w * h4.w;
    }
    a0 += __shfl_xor(a0, 1);
    a1 += __shfl_xor(a1, 1);
    a2 += __shfl_xor(a2, 1);

    if (kh == 0) {
      const float hp = hs[item * WST + col];
      const float r = sigm(xr + a0 + bv0);
      const float z = sigm(xz + a1 + bv1);
      // n = tanh(xn + r * hn), hn = (h @ Whh_n^T + bhh_n)  [round-3 bug: r* was missing]
      const float n = tanhf(xn + r * (a2 + bv2));
      const float hnew = (1.f - z) * n + z * hp;
      float* Hn = (s & 1) ? H0 : H1;
      Hn[((size_t)b << 9) + col] = hnew;
      if (out_seq) out_seq[((size_t)(b * S + xidx) << 9) + col] = hnew;
    }
    if (s + 1 < seqlen) {
      tgt += 32;
      group_barrier(cell, tgt);
    }
  }
}

// Fallback per-step GRU kernel (round-1 proven, grid 192).
__global__ __launch_bounds__(256) void k_gru_step(
    const float* __restrict__ Whh_f, const float* __restrict__ bhh_f,
    const float* __restrict__ Whh_b, const float* __restrict__ bhh_b,
    const float* __restrict__ qWhh,  const float* __restrict__ qbhh,
    const float* __restrict__ gx_f, const float* __restrict__ gx_b,
    const float* __restrict__ gx_q,
    const float* __restrict__ Hf_prev, float* __restrict__ Hf_next,
    const float* __restrict__ Hb_prev, float* __restrict__ Hb_next,
    const float* __restrict__ Hq_prev, float* __restrict__ Hq_next,
    float* __restrict__ facts, float* __restrict__ hb_all, int s) {
  const int bx  = blockIdx.x;
  const int gru = bx >> 6;
  const int ib  = (bx >> 4) & 3;
  const int jb  = bx & 15;
  if (gru == 2 && s >= TQ) return;
  const float* Whh; const float* bhh; const float* gx; const float* Hp; float* Hn;
  int xidx, seqlen;
  if (gru == 0)      { Whh = Whh_f; bhh = bhh_f; gx = gx_f; Hp = Hf_prev; Hn = Hf_next; xidx = s;         seqlen = S;  }
  else if (gru == 1) { Whh = Whh_b; bhh = bhh_b; gx = gx_b; Hp = Hb_prev; Hn = Hb_next; xidx = S - 1 - s; seqlen = S;  }
  else               { Whh = qWhh;  bhh = qbhh;  gx = gx_q; Hp = Hq_prev; Hn = Hq_next; xidx = s;         seqlen = TQ; }
  __shared__ __align__(16) float hs[16][516];
  __shared__ float gd[96][17];
  const int t = threadIdx.x;
  if (s == 0) {
    for (int i = t; i < 16 * 512; i += 256) hs[i >> 9][i & 511] = 0.f;
  } else {
    for (int i = t; i < 16 * 128; i += 256) {
      const int item = i >> 7, c4 = (i & 127) << 2;
      *(float4*)&hs[item][c4] = *(const float4*)(Hp + ((size_t)(ib * 16 + item) << 9) + c4);
    }
  }
  __syncthreads();
  {
    const int item = t & 15;
    const int rw   = t >> 4;
    const float4* wp[6];
#pragma unroll
    for (int rr = 0; rr < 6; ++rr) {
      const int row_local = rw + (rr << 4);
      const int gate = row_local >> 5;
      const int wrow = (gate << 9) + (jb << 5) + (row_local & 31);
      wp[rr] = (const float4*)(Whh + ((size_t)wrow << 9));
    }
    float acc[6] = {};
#pragma unroll 2
    for (int k4 = 0; k4 < 128; ++k4) {
      const float4 h4 = *(const float4*)&hs[item][k4 << 2];
#pragma unroll
      for (int rr = 0; rr < 6; ++rr) {
        const float4 w4 = wp[rr][k4];
        acc[rr] += w4.x * h4.x + w4.y * h4.y + w4.z * h4.z + w4.w * h4.w;
      }
    }
#pragma unroll
    for (int rr = 0; rr < 6; ++rr) gd[rw + (rr << 4)][item] = acc[rr];
  }
  __syncthreads();
  for (int p = t; p < 512; p += 256) {
    const int it2 = p >> 5;
    const int cl  = p & 31;
    const int col = (jb << 5) + cl;
    const int b   = (ib << 4) + it2;
    const size_t gxrow = ((size_t)b * seqlen + xidx) * 1536;
    const float xr = gx[gxrow + col];
    const float xz = gx[gxrow + 512 + col];
    const float xn = gx[gxrow + 1024 + col];
    const float hr = gd[cl][it2]      + bhh[col];
    const float hz = gd[32 + cl][it2] + bhh[512 + col];
    const float hn = gd[64 + cl][it2] + bhh[1024 + col];
    const float hp = hs[it2][col];
    const float r = sigm(xr + hr);
    const float z = sigm(xz + hz);
    const float n = tanhf(xn + r * hn);
    const float hnew = (1.f - z) * n + z * hp;
    Hn[((size_t)b << 9) + col] = hnew;
    if (gru == 0)      facts[((size_t)(b * S + s) << 9) + col]     = hnew;
    else if (gru == 1) hb_all[((size_t)(b * S + xidx) << 9) + col] = hnew;
  }
}

__global__ __launch_bounds__(256) void k_add(float* __restrict__ a, const float* __restrict__ b) {
  const size_t i = (((size_t)blockIdx.x << 8) + threadIdx.x) << 2;
  float4 x = *(float4*)(a + i);
  const float4 y = *(const float4*)(b + i);
  x.x += y.x; x.y += y.y; x.z += y.z; x.w += y.w;
  *(float4*)(a + i) = x;
}

// z (bf16) = [f*q, f*M, |f-q|, |f-M|]
__global__ __launch_bounds__(256) void k_build_z16(const float* __restrict__ facts,
                                                   const float* __restrict__ q,
                                                   const float* __restrict__ M,
                                                   ushort_t* __restrict__ z) {
  const int bs = blockIdx.x;
  const int b  = bs >> 6;
  const int t  = threadIdx.x;
  const size_t zb = (size_t)bs << 11;
  for (int c = t; c < 512; c += 256) {
    const float f  = facts[((size_t)bs << 9) + c];
    const float qv = q[(b << 9) + c];
    const float mv = M[(b << 9) + c];
    z[zb + c]        = f2bf(f * qv);
    z[zb + 512 + c]  = f2bf(f * mv);
    z[zb + 1024 + c] = f2bf(fabsf(f - qv));
    z[zb + 1536 + c] = f2bf(fabsf(f - mv));
  }
}

__global__ __launch_bounds__(256) void k_score_softmax(const float* __restrict__ g1,
                                                       const float* __restrict__ z2w,
                                                       const float* __restrict__ z2b,
                                                       float* __restrict__ G) {
  const int b = blockIdx.x, t = threadIdx.x;
  const int wave = t >> 6, lane = t & 63;
  __shared__ float sc[64];
  for (int si = 0; si < 16; ++si) {
    const int s = wave * 16 + si;
    const float* row = g1 + ((size_t)(b * S + s) << 9) + lane * 8;
    const float* w   = z2w + lane * 8;
    float p = 0.f;
#pragma unroll
    for (int k = 0; k < 8; ++k) p += row[k] * w[k];
#pragma unroll
    for (int off = 32; off; off >>= 1) p += __shfl_xor(p, off);
    if (lane == 0) sc[s] = p + z2b[0];
  }
  __syncthreads();
  if (wave == 0) {
    const float v = sc[lane];
    float m = v;
#pragma unroll
    for (int off = 32; off; off >>= 1) m = fmaxf(m, __shfl_xor(m, off));
    const float e = expf(v - m);
    float su = e;
#pragma unroll
    for (int off = 32; off; off >>= 1) su += __shfl_xor(su, off);
    G[(b << 6) + lane] = e / su;
  }
}

// ---------------------------------------------------------------------------
// Persistent AGRU scan: 256 WGs = 8 ib (8 items) x 32 jb (16 cols).
// Weights (UrT/UT col slices) LDS-resident; group-local barriers per ib.
// Thread = (item, col, which-matrix) + shfl combine.
// ---------------------------------------------------------------------------
__global__ __launch_bounds__(256) void k_agru_scan3(
    const float* __restrict__ UrT, const float* __restrict__ UT,
    const float* __restrict__ fRW, const float* __restrict__ fW,
    const float* __restrict__ br, const float* __restrict__ G,
    float* __restrict__ C0, float* __restrict__ C1,
    unsigned* __restrict__ bar) {
  const int ib = blockIdx.x >> 5;
  const int jb = blockIdx.x & 31;
  __shared__ __align__(16) float wlds[32 * WST];
  __shared__ __align__(16) float cs[8 * WST];
  const int t = threadIdx.x;

  for (int i = t; i < 16 * 128; i += 256) {
    const int c = i >> 7, k4 = (i & 127) << 2;
    *(float4*)&wlds[c * WST + k4] =
        *(const float4*)(UrT + (((size_t)((jb << 4) + c)) << 9) + k4);
    *(float4*)&wlds[(16 + c) * WST + k4] =
        *(const float4*)(UT + (((size_t)((jb << 4) + c)) << 9) + k4);
  }

  const int which = t & 1;
  const int cl    = (t >> 1) & 15;
  const int item  = t >> 5;
  const int col   = (jb << 4) + cl;
  const int b     = (ib << 3) + item;
  const float brv = br[col];
  const float4* wp = (const float4*)&wlds[((which << 4) + cl) * WST];
  const float4* csp = (const float4*)&cs[item * WST];
  unsigned* cell = bar + ib * 64;
  unsigned tgt = 0;

  for (int s = 0; s < S; ++s) {
    if (s == 0) {
      for (int i = t; i < 8 * 128; i += 256) {
        const int it = i >> 7, k4 = (i & 127) << 2;
        *(float4*)&cs[it * WST + k4] = float4{0.f, 0.f, 0.f, 0.f};
      }
    } else {
      const float* Cp = (s & 1) ? C1 : C0;
      for (int i = t; i < 8 * 128; i += 256) {
        const int it = i >> 7, k4 = (i & 127) << 2;
        *(float4*)&cs[it * WST + k4] =
            *(const float4*)(Cp + ((size_t)((ib << 3) + it) << 9) + k4);
      }
    }
    __syncthreads();

    float fr = 0.f, fw = 0.f, g = 0.f;
    if (which == 0) {
      const size_t fi = ((size_t)(b * S + s) << 9) + col;
      fr = fRW[fi];
      fw = fW[fi];
      g  = G[(b << 6) + s];
    }

    float acc = 0.f;
#pragma unroll 4
    for (int k4 = 0; k4 < 128; ++k4) {
      const float4 c4v = csp[k4];
      const float4 w4 = wp[k4];
      acc += w4.x * c4v.x + w4.y * c4v.y + w4.z * c4v.z + w4.w * c4v.w;
    }
    const float other = __shfl_xor(acc, 1);

    if (which == 0) {
      const float a0 = acc;    // c @ Ur col
      const float a1 = other;  // c @ U col
      const float r  = sigm(fr + a0 + brv);
      const float ht = tanhf(fw + r * a1 + brv);
      const float cp = cs[item * WST + col];
      float* Cn = (s & 1) ? C0 : C1;
      Cn[((size_t)b << 9) + col] = g * ht + (1.f - g) * cp;
    }
    if (s + 1 < S) {
      tgt += 32;
      group_barrier(cell, tgt);
    }
  }
}

// Fallback per-step AGRU kernel (round-1 proven, grid 128).
__global__ __launch_bounds__(256) void k_agru_step(
    const float* __restrict__ UrT, const float* __restrict__ UT,
    const float* __restrict__ fRW, const float* __restrict__ fW,
    const float* __restrict__ br, const float* __restrict__ G,
    const float* __restrict__ Cprev, float* __restrict__ Cnext, int s) {
  const int ib = blockIdx.x >> 5;
  const int jb = blockIdx.x & 31;
  const int t  = threadIdx.x;
  __shared__ __align__(16) float cs[16][516];
  if (s == 0) {
    for (int i = t; i < 16 * 512; i += 256) cs[i >> 9][i & 511] = 0.f;
  } else {
    for (int i = t; i < 16 * 128; i += 256) {
      const int item = i >> 7, c4 = (i & 127) << 2;
      *(float4*)&cs[item][c4] = *(const float4*)(Cprev + ((size_t)(ib * 16 + item) << 9) + c4);
    }
  }
  __syncthreads();
  const int item = t >> 4;
  const int cl   = t & 15;
  const int col  = (jb << 4) + cl;
  const int b    = (ib << 4) + item;
  const float4* w0 = (const float4*)(UrT + ((size_t)col << 9));
  const float4* w1 = (const float4*)(UT  + ((size_t)col << 9));
  float acc0 = 0.f, acc1 = 0.f;
#pragma unroll 4
  for (int k4 = 0; k4 < 128; ++k4) {
    const float4 c4v = *(const float4*)&cs[item][k4 << 2];
    const float4 a = w0[k4];
    const float4 d = w1[k4];
    acc0 += a.x * c4v.x + a.y * c4v.y + a.z * c4v.z + a.w * c4v.w;
    acc1 += d.x * c4v.x + d.y * c4v.y + d.z * c4v.z + d.w * c4v.w;
  }
  const float g   = G[(b << 6) + s];
  const size_t fi = ((size_t)(b * S + s) << 9) + col;
  const float brv = br[col];
  const float r  = sigm(fRW[fi] + acc0 + brv);
  const float ht = tanhf(fW[fi] + r * acc1 + brv);
  const float cp = cs[item][col];
  Cnext[((size_t)b << 9) + col] = g * ht + (1.f - g) * cp;
}

__global__ __launch_bounds__(256) void k_concat3(const float* __restrict__ M,
                                                 const float* __restrict__ C,
                                                 const float* __restrict__ q,
                                                 float* __restrict__ out) {
  const int b = blockIdx.x, t = threadIdx.x;
  for (int c = t; c < 512; c += 256) {
    out[(size_t)b * 1536 + c]        = M[(b << 9) + c];
    out[(size_t)b * 1536 + 512 + c]  = C[(b << 9) + c];
    out[(size_t)b * 1536 + 1024 + c] = q[(b << 9) + c];
  }
}

__global__ __launch_bounds__(256) void k_concat2(const float* __restrict__ M,
                                                 const float* __restrict__ q,
                                                 float* __restrict__ out) {
  const int b = blockIdx.x, t = threadIdx.x;
  for (int c = t; c < 512; c += 256) {
    out[(size_t)b * 1024 + c]       = M[(b << 9) + c];
    out[(size_t)b * 1024 + 512 + c] = q[(b << 9) + c];
  }
}

}  // namespace

extern "C" void kernel_launch(void* const* d_in, const int* in_sizes, int n_in,
                              void* d_out, int out_size, void* d_ws, size_t ws_size,
                              hipStream_t stream) {
  const int*   contexts  = (const int*)d_in[0];
  const int*   questions = (const int*)d_in[1];
  const float* emb   = (const float*)d_in[2];
  const float* Wih_f = (const float*)d_in[3];
  const float* Whh_f = (const float*)d_in[4];
  const float* bih_f = (const float*)d_in[5];
  const float* bhh_f = (const float*)d_in[6];
  const float* Wih_b = (const float*)d_in[7];
  const float* Whh_b = (const float*)d_in[8];
  const float* bih_b = (const float*)d_in[9];
  const float* bhh_b = (const float*)d_in[10];
  const float* qWih  = (const float*)d_in[11];
  const float* qWhh  = (const float*)d_in[12];
  const float* qbih  = (const float*)d_in[13];
  const float* qbhh  = (const float*)d_in[14];
  const float* Wr    = (const float*)d_in[15];
  const float* Ur    = (const float*)d_in[16];
  const float* br    = (const float*)d_in[17];
  const float* Wm    = (const float*)d_in[18];
  const float* Um    = (const float*)d_in[19];
  const float* z1_w  = (const float*)d_in[20];
  const float* z1_b  = (const float*)d_in[21];
  const float* z2_w  = (const float*)d_in[22];
  const float* z2_b  = (const float*)d_in[23];
  const float* nm_w  = (const float*)d_in[24];
  const float* nm_b  = (const float*)d_in[25];
  const float* ans_w = (const float*)d_in[26];
  const float* ans_b = (const float*)d_in[27];
  (void)in_sizes; (void)n_in; (void)out_size; (void)ws_size;

  float* ws = (float*)d_ws;
  float* WrT      = ws + 0;          // 262144
  float* UrT      = ws + 262144;     // 262144
  float* WT       = ws + 524288;     // 262144
  float* UT       = ws + 786432;     // 262144
  float* facts_in = ws + 1048576;    // 2097152  (reused as fRW)
  float* qe       = ws + 3145728;    // 1048576
  float* gx_f     = ws + 4194304;    // 6291456  (reused as z bf16)
  float* gx_b     = ws + 10485760;   // 6291456
  float* gx_q     = ws + 16777216;   // 3145728  (reused as g1)
  float* facts    = ws + 19922944;   // 2097152
  float* hb       = ws + 22020096;   // 2097152  (reused as fW)
  float* Hbuf     = ws + 24117248;   // 196608
  float* C0       = ws + 24313856;   // 32768
  float* C1       = ws + 24346624;   // 32768
  float* M0       = ws + 24379392;   // 32768
  float* M1       = ws + 24412160;   // 32768
  float* MCq      = ws + 24444928;   // 98304
  float* Mq       = ws + 24543232;   // 65536  (barrier cells live here early)
  float* Gm       = ws + 24608768;   // 4096
  ushort_t* zb16 = (ushort_t*)gx_f;
  float* g1  = gx_q;
  float* fRW = facts_in;
  float* fW  = hb;
  float* preds = (float*)d_out;
  unsigned* bar = (unsigned*)Mq;     // 48 cells x 64 u32 = 12 KB; Mq used only in stage F

  float* Hf[2]  = {Hbuf,          Hbuf + 32768};
  float* Hb2[2] = {Hbuf + 65536,  Hbuf + 98304};
  float* Hq[2]  = {Hbuf + 131072, Hbuf + 163840};
  float* q = Hq[0];
  float* Cb[2] = {C0, C1};

  // ---- barrier cells: zero once per call (monotonic counters) ----
  hipMemsetAsync(bar, 0, 48 * 64 * sizeof(unsigned), stream);

  // ---- stage A: embeddings + weight transposes ----
  k_embed_facts<<<B * S, 256, 0, stream>>>(contexts, emb, facts_in);
  k_embed_q<<<B * TQ, 256, 0, stream>>>(questions, emb, qe);
  dim3 tb(32, 8);
  k_transpose512<<<dim3(16, 16), tb, 0, stream>>>(Wr, WrT);
  k_transpose512<<<dim3(16, 16), tb, 0, stream>>>(Ur, UrT);
  k_transpose512<<<dim3(16, 16), tb, 0, stream>>>(Wm, WT);
  k_transpose512<<<dim3(16, 16), tb, 0, stream>>>(Um, UT);

  // ---- stage B: input-side gate GEMMs (f32, feeds recurrence) ----
  k_gemm_nt<0><<<dim3(24, 64), 256, 0, stream>>>(facts_in, Wih_f, bih_f, gx_f, 4096, 1536, 512);
  k_gemm_nt<0><<<dim3(24, 64), 256, 0, stream>>>(facts_in, Wih_b, bih_b, gx_b, 4096, 1536, 512);
  k_gemm_nt<0><<<dim3(24, 32), 256, 0, stream>>>(qe, qWih, qbih, gx_q, 2048, 1536, 512);

  // ---- stage C: persistent GRU scans (fwd, bwd, question) ----
  {
    bool ok = true;
    {
      int seqlen = S, rev = 0;
      void* a[] = { (void*)&Whh_f, (void*)&bhh_f, (void*)&gx_f, (void*)&Hf[0],
                    (void*)&Hf[1], (void*)&facts, (void*)&seqlen, (void*)&rev,
                    (void*)&bar };
      ok = ok && hipLaunchCooperativeKernel(reinterpret_cast<void*>(k_gru_scan3),
                                            dim3(256), dim3(256), a, 0, stream) == hipSuccess;
    }
    if (ok) {
      int seqlen = S, rev = 1;
      unsigned* bb = bar + 8 * 64;
      void* a[] = { (void*)&Whh_b, (void*)&bhh_b, (void*)&gx_b, (void*)&Hb2[0],
                    (void*)&Hb2[1], (void*)&hb, (void*)&seqlen, (void*)&rev,
                    (void*)&bb };
      ok = hipLaunchCooperativeKernel(reinterpret_cast<void*>(k_gru_scan3),
                                      dim3(256), dim3(256), a, 0, stream) == hipSuccess;
    }
    if (ok) {
      int seqlen = TQ, rev = 0;
      float* nullout = nullptr;
      unsigned* bq = bar + 16 * 64;
      void* a[] = { (void*)&qWhh, (void*)&qbhh, (void*)&gx_q, (void*)&Hq[0],
                    (void*)&Hq[1], (void*)&nullout, (void*)&seqlen, (void*)&rev,
                    (void*)&bq };
      ok = hipLaunchCooperativeKernel(reinterpret_cast<void*>(k_gru_scan3),
                                      dim3(256), dim3(256), a, 0, stream) == hipSuccess;
    }
    if (!ok) {
      // fallback: per-step kernels recompute all three GRUs from scratch
      for (int s = 0; s < S; ++s)
        k_gru_step<<<192, 256, 0, stream>>>(Whh_f, bhh_f, Whh_b, bhh_b, qWhh, qbhh,
                                            gx_f, gx_b, gx_q,
                                            Hf[s & 1], Hf[(s + 1) & 1],
                                            Hb2[s & 1], Hb2[(s + 1) & 1],
                                            Hq[s & 1], Hq[(s + 1) & 1],
                                            facts, hb, s);
    }
  }
  k_add<<<2048, 256, 0, stream>>>(facts, hb);

  // ---- stage D: hop-invariant precomputes ----
  k_gemm_nt<0><<<dim3(8, 64), 256, 0, stream>>>(facts, WrT, nullptr, fRW, 4096, 512, 512);
  k_gemm_nt<0><<<dim3(8, 64), 256, 0, stream>>>(facts, WT,  nullptr, fW,  4096, 512, 512);

  // ---- stage E: episodic memory hops ----
  const float* Mcur = q;
  for (int h = 0; h < 3; ++h) {
    k_build_z16<<<B * S, 256, 0, stream>>>(facts, q, Mcur, zb16);
    k_gemm_mfma<true, 1><<<dim3(8, 64), 256, 0, stream>>>(zb16, z1_w, z1_b, g1, 4096, 512, 2048);
    k_score_softmax<<<B, 256, 0, stream>>>(g1, z2_w, z2_b, Gm);
    {
      unsigned* ba = bar + (24 + h * 8) * 64;
      void* a[] = { (void*)&UrT, (void*)&UT, (void*)&fRW, (void*)&fW,
                    (void*)&br, (void*)&Gm, (void*)&C0, (void*)&C1, (void*)&ba };
      hipError_t e = hipLaunchCooperativeKernel(reinterpret_cast<void*>(k_agru_scan3),
                                                dim3(256), dim3(256), a, 0, stream);
      if (e != hipSuccess) {
        for (int s = 0; s < S; ++s)
          k_agru_step<<<128, 256, 0, stream>>>(UrT, UT, fRW, fW, br, Gm,
                                               Cb[s & 1], Cb[(s + 1) & 1], s);
      }
    }
    k_concat3<<<B, 256, 0, stream>>>(Mcur, C0, q, MCq);
    float* Mnext = (h & 1) ? M1 : M0;
    k_gemm_nt<2><<<dim3(8, 1), 256, 0, stream>>>(MCq, nm_w, nm_b, Mnext, 64, 512, 1536);
    Mcur = Mnext;
  }

  // ---- stage F: answer projection ----
  k_concat2<<<B, 256, 0, stream>>>(Mcur, q, Mq);
  k_gemm_mfma<false, 0><<<dim3(500, 1), 256, 0, stream>>>(Mq, ans_w, ans_b, preds, 64, 32000, 1024);
}

// Round 5
// 3127.752 us; speedup vs baseline: 3.0180x; 2.3360x over previous
//
#include <hip/hip_runtime.h>
#include <cstddef>
#include <cstdint>

namespace {

constexpr int H  = 512;
constexpr int V  = 32000;
constexpr int B  = 64;
constexpr int S  = 64;
constexpr int T  = 32;
constexpr int TQ = 32;

// LDS row stride for scan kernels: 520 floats -> start bank = row*2 mod 32,
// 2-way max aliasing (free, m136).
constexpr int WST = 520;

typedef unsigned short ushort_t;
typedef __attribute__((ext_vector_type(8))) short bf16x8;
typedef __attribute__((ext_vector_type(4))) float f32x4;

__device__ __forceinline__ ushort_t f2bf(float f) {
  union { float f; unsigned u; } v; v.f = f;
  return (ushort_t)((v.u + 0x7FFFu + ((v.u >> 16) & 1u)) >> 16);
}

__device__ __forceinline__ float sigm(float x) { return 1.f / (1.f + expf(-x)); }

// ---- cross-XCD coherent data movement (bypass non-coherent L1/L2) ----------
// sc0 sc1 loads/stores hit the device coherence point; this replaces the
// catastrophic __threadfence() (full per-XCD L2 writeback+invalidate) that
// cost ~19us/step in round 4.
__device__ __forceinline__ f32x4 load4c(const float* p) {
  f32x4 v;
  asm volatile("global_load_dwordx4 %0, %1, off sc0 sc1" : "=v"(v) : "v"(p));
  return v;
}
__device__ __forceinline__ void store1c(float* p, float v) {
  asm volatile("global_store_dword %0, %1, off sc0 sc1" :: "v"(p), "v"(v) : "memory");
}
__device__ __forceinline__ void waitvm0() {
  asm volatile("s_waitcnt vmcnt(0)" ::: "memory");
  __builtin_amdgcn_sched_barrier(0);
}

// Group-local barrier, no fences. Caller must have issued its coherent (sc1)
// stores beforehand; waitvm0 inside is the per-thread release. Counter cell is
// monotonic (zeroed once per launch batch).
__device__ __forceinline__ void group_barrier_nc(unsigned* cell, unsigned target) {
  waitvm0();          // own stores reached coherence point
  __syncthreads();    // whole WG released
  if (threadIdx.x == 0) {
    __hip_atomic_fetch_add(cell, 1u, __ATOMIC_RELAXED, __HIP_MEMORY_SCOPE_AGENT);
    unsigned v;
    do {
      v = __hip_atomic_load(cell, __ATOMIC_RELAXED, __HIP_MEMORY_SCOPE_AGENT);
      if (v < target) __builtin_amdgcn_s_sleep(2);
    } while (v < target);
  }
  __syncthreads();
}

// ---------------------------------------------------------------------------
// Embedding + positional encoding
// ---------------------------------------------------------------------------
__global__ __launch_bounds__(256) void k_embed_facts(const int* __restrict__ ctx,
                                                     const float* __restrict__ emb,
                                                     float* __restrict__ facts_in) {
  const int bs = blockIdx.x;
  const int s  = bs & (S - 1);
  const int t  = threadIdx.x;
  __shared__ int sidx[T];
  if (t < T) sidx[t] = ctx[(size_t)bs * T + t];
  __syncthreads();
  float a0 = 0.f, a1 = 0.f;
  for (int tt = 0; tt < T; ++tt) {
    const int ix = sidx[tt];
    if (ix != 0) {
      const float* e = emb + ((size_t)ix << 9);
      a0 += e[t];
      a1 += e[t + 256];
    }
  }
  const float sf = (float)s * (1.f / 64.f);
  const float c1 = 1.f - sf;
  const float c2 = (1.f - 2.f * sf) * (1.f / 512.f);
  facts_in[((size_t)bs << 9) + t]       = a0 * (c1 - (float)t * c2);
  facts_in[((size_t)bs << 9) + t + 256] = a1 * (c1 - (float)(t + 256) * c2);
}

__global__ __launch_bounds__(256) void k_embed_q(const int* __restrict__ qidx,
                                                 const float* __restrict__ emb,
                                                 float* __restrict__ qe) {
  const int bt = blockIdx.x;
  const int t  = threadIdx.x;
  const int ix = qidx[bt];
  float v0 = 0.f, v1 = 0.f;
  if (ix != 0) {
    const float* e = emb + ((size_t)ix << 9);
    v0 = e[t];
    v1 = e[t + 256];
  }
  qe[((size_t)bt << 9) + t]       = v0;
  qe[((size_t)bt << 9) + t + 256] = v1;
}

__global__ __launch_bounds__(256) void k_transpose512(const float* __restrict__ src,
                                                      float* __restrict__ dst) {
  __shared__ float tile[32][33];
  const int x0 = blockIdx.x * 32, y0 = blockIdx.y * 32;
  for (int i = threadIdx.y; i < 32; i += 8)
    tile[i][threadIdx.x] = src[(size_t)(y0 + i) * H + x0 + threadIdx.x];
  __syncthreads();
  for (int i = threadIdx.y; i < 32; i += 8)
    dst[(size_t)(x0 + i) * H + y0 + threadIdx.x] = tile[threadIdx.x][i];
}

// ---------------------------------------------------------------------------
// f32 GEMM (NT): C = act(A[M,K] @ B[N,K]^T + bias). 64x64 tile.
// ---------------------------------------------------------------------------
template <int ACT>
__global__ __launch_bounds__(256) void k_gemm_nt(const float* __restrict__ A,
                                                 const float* __restrict__ Bm,
                                                 const float* __restrict__ bias,
                                                 float* __restrict__ C,
                                                 int M, int N, int K) {
  __shared__ __align__(16) float As[32][68];
  __shared__ __align__(16) float Bs[32][68];
  const int t  = threadIdx.x;
  const int tx = t & 15, ty = t >> 4;
  const int m0 = blockIdx.y << 6, n0 = blockIdx.x << 6;
  const int lrow = t >> 3;
  const int lcol = (t & 7) << 2;
  float acc[4][4] = {};
  for (int k0 = 0; k0 < K; k0 += 32) {
    const float4 a0 = *(const float4*)(A  + (size_t)(m0 + lrow) * K      + k0 + lcol);
    const float4 a1 = *(const float4*)(A  + (size_t)(m0 + lrow + 32) * K + k0 + lcol);
    const float4 b0 = *(const float4*)(Bm + (size_t)(n0 + lrow) * K      + k0 + lcol);
    const float4 b1 = *(const float4*)(Bm + (size_t)(n0 + lrow + 32) * K + k0 + lcol);
    __syncthreads();
    As[lcol + 0][lrow] = a0.x; As[lcol + 1][lrow] = a0.y; As[lcol + 2][lrow] = a0.z; As[lcol + 3][lrow] = a0.w;
    As[lcol + 0][lrow + 32] = a1.x; As[lcol + 1][lrow + 32] = a1.y; As[lcol + 2][lrow + 32] = a1.z; As[lcol + 3][lrow + 32] = a1.w;
    Bs[lcol + 0][lrow] = b0.x; Bs[lcol + 1][lrow] = b0.y; Bs[lcol + 2][lrow] = b0.z; Bs[lcol + 3][lrow] = b0.w;
    Bs[lcol + 0][lrow + 32] = b1.x; Bs[lcol + 1][lrow + 32] = b1.y; Bs[lcol + 2][lrow + 32] = b1.z; Bs[lcol + 3][lrow + 32] = b1.w;
    __syncthreads();
#pragma unroll 4
    for (int kk = 0; kk < 32; ++kk) {
      float a[4], b[4];
      *(float4*)a = *(const float4*)&As[kk][ty << 2];
      *(float4*)b = *(const float4*)&Bs[kk][tx << 2];
#pragma unroll
      for (int i = 0; i < 4; ++i)
#pragma unroll
        for (int j = 0; j < 4; ++j) acc[i][j] += a[i] * b[j];
    }
  }
#pragma unroll
  for (int i = 0; i < 4; ++i) {
    const int m = m0 + (ty << 2) + i;
#pragma unroll
    for (int j = 0; j < 4; ++j) {
      const int n = n0 + (tx << 2) + j;
      float v = acc[i][j];
      if (bias) v += bias[n];
      if (ACT == 1) v = tanhf(v);
      if (ACT == 2) v = fmaxf(v, 0.f);
      C[(size_t)m * N + n] = v;
    }
  }
}

// ---------------------------------------------------------------------------
// bf16 MFMA GEMM (NT), validated in round 2.
// ---------------------------------------------------------------------------
template <bool A_BF16, int ACT>
__global__ __launch_bounds__(256) void k_gemm_mfma(const void* __restrict__ Av,
                                                   const float* __restrict__ Bm,
                                                   const float* __restrict__ bias,
                                                   float* __restrict__ C,
                                                   int M, int N, int K) {
  __shared__ __align__(16) ushort_t As[64][72];
  __shared__ __align__(16) ushort_t Bs[64][72];
  const int t    = threadIdx.x;
  const int lane = t & 63;
  const int w    = t >> 6;
  const int wr   = w >> 1, wc = w & 1;
  const int m0 = blockIdx.y << 6, n0 = blockIdx.x << 6;
  const int row = t >> 2;
  const int ch  = t & 3;

  f32x4 acc[2][2] = {};

  for (int k0 = 0; k0 < K; k0 += 64) {
    if (A_BF16) {
      const ushort_t* A16 = (const ushort_t*)Av;
#pragma unroll
      for (int cc = 0; cc < 2; ++cc) {
        const int c8 = ch + cc * 4;
        const uint4 v = *(const uint4*)(A16 + (size_t)(m0 + row) * K + k0 + c8 * 8);
        *(uint4*)&As[row][c8 * 8] = v;
      }
    } else {
      const float* Af = (const float*)Av;
#pragma unroll
      for (int cc = 0; cc < 2; ++cc) {
        const int c8 = ch + cc * 4;
        const float* src = Af + (size_t)(m0 + row) * K + k0 + c8 * 8;
        const float4 f0 = *(const float4*)src;
        const float4 f1 = *(const float4*)(src + 4);
        uint4 v;
        v.x = (unsigned)f2bf(f0.x) | ((unsigned)f2bf(f0.y) << 16);
        v.y = (unsigned)f2bf(f0.z) | ((unsigned)f2bf(f0.w) << 16);
        v.z = (unsigned)f2bf(f1.x) | ((unsigned)f2bf(f1.y) << 16);
        v.w = (unsigned)f2bf(f1.z) | ((unsigned)f2bf(f1.w) << 16);
        *(uint4*)&As[row][c8 * 8] = v;
      }
    }
    {
#pragma unroll
      for (int cc = 0; cc < 2; ++cc) {
        const int c8 = ch + cc * 4;
        const float* src = Bm + (size_t)(n0 + row) * K + k0 + c8 * 8;
        const float4 f0 = *(const float4*)src;
        const float4 f1 = *(const float4*)(src + 4);
        uint4 v;
        v.x = (unsigned)f2bf(f0.x) | ((unsigned)f2bf(f0.y) << 16);
        v.y = (unsigned)f2bf(f0.z) | ((unsigned)f2bf(f0.w) << 16);
        v.z = (unsigned)f2bf(f1.x) | ((unsigned)f2bf(f1.y) << 16);
        v.w = (unsigned)f2bf(f1.z) | ((unsigned)f2bf(f1.w) << 16);
        *(uint4*)&Bs[row][c8 * 8] = v;
      }
    }
    __syncthreads();
#pragma unroll
    for (int ks = 0; ks < 2; ++ks) {
      bf16x8 a[2], b[2];
#pragma unroll
      for (int fr = 0; fr < 2; ++fr)
        a[fr] = *(const bf16x8*)&As[wr * 32 + fr * 16 + (lane & 15)][ks * 32 + (lane >> 4) * 8];
#pragma unroll
      for (int fc = 0; fc < 2; ++fc)
        b[fc] = *(const bf16x8*)&Bs[wc * 32 + fc * 16 + (lane & 15)][ks * 32 + (lane >> 4) * 8];
#pragma unroll
      for (int fr = 0; fr < 2; ++fr)
#pragma unroll
        for (int fc = 0; fc < 2; ++fc)
          acc[fr][fc] = __builtin_amdgcn_mfma_f32_16x16x32_bf16(a[fr], b[fc], acc[fr][fc], 0, 0, 0);
    }
    __syncthreads();
  }
#pragma unroll
  for (int fr = 0; fr < 2; ++fr) {
#pragma unroll
    for (int fc = 0; fc < 2; ++fc) {
      const int rbase = m0 + wr * 32 + fr * 16 + ((lane >> 4) << 2);
      const int col   = n0 + wc * 32 + fc * 16 + (lane & 15);
      const float bv  = bias ? bias[col] : 0.f;
#pragma unroll
      for (int j = 0; j < 4; ++j) {
        float v = acc[fr][fc][j] + bv;
        if (ACT == 1) v = tanhf(v);
        if (ACT == 2) v = fmaxf(v, 0.f);
        C[(size_t)(rbase + j) * N + col] = v;
      }
    }
  }
}

// ---------------------------------------------------------------------------
// Persistent GRU scan. 256 WGs = 8 ib (8 items) x 32 jb (16 cols).
// Weights LDS-resident; h exchanged via sc1 coherent stores/loads;
// fence-free group barrier.
// ---------------------------------------------------------------------------
__global__ __launch_bounds__(256) void k_gru_scan3(
    const float* __restrict__ Whh, const float* __restrict__ bhh,
    const float* __restrict__ gx, float* __restrict__ H0, float* __restrict__ H1,
    float* __restrict__ out_seq, int seqlen, int rev,
    unsigned* __restrict__ bar) {
  const int ib = blockIdx.x >> 5;
  const int jb = blockIdx.x & 31;
  __shared__ __align__(16) float wlds[48 * WST];
  __shared__ __align__(16) float hs[8 * WST];
  const int t = threadIdx.x;

  // stage weight slice once: rows g*16+c <- Whh[g*512 + jb*16 + c][:]
  for (int i = t; i < 48 * 128; i += 256) {
    const int row = i >> 7, k4 = (i & 127) << 2;
    const int g = row >> 4, c = row & 15;
    *(float4*)&wlds[row * WST + k4] =
        *(const float4*)(Whh + ((size_t)(g * 512 + (jb << 4) + c) << 9) + k4);
  }

  const int kh   = t & 1;
  const int cl   = (t >> 1) & 15;
  const int item = t >> 5;
  const int col  = (jb << 4) + cl;
  const int b    = (ib << 3) + item;
  const float bv0 = bhh[col];
  const float bv1 = bhh[512 + col];
  const float bv2 = bhh[1024 + col];
  const float4* w0 = (const float4*)&wlds[(cl) * WST + (kh << 8)];
  const float4* w1 = (const float4*)&wlds[(16 + cl) * WST + (kh << 8)];
  const float4* w2 = (const float4*)&wlds[(32 + cl) * WST + (kh << 8)];
  const float4* hsp = (const float4*)&hs[item * WST + (kh << 8)];
  unsigned* cell = bar + ib * 64;
  unsigned tgt = 0;

  for (int s = 0; s < seqlen; ++s) {
    // stage h state for this step
    if (s == 0) {
      for (int i = t; i < 8 * 128; i += 256) {
        const int it = i >> 7, k4 = (i & 127) << 2;
        *(float4*)&hs[it * WST + k4] = float4{0.f, 0.f, 0.f, 0.f};
      }
    } else {
      const float* Hp = (s & 1) ? H1 : H0;
      // coherent (cache-bypassing) loads: producer WGs are on other XCDs
      f32x4 v[4];
#pragma unroll
      for (int u = 0; u < 4; ++u) {
        const int i = t + (u << 8);
        v[u] = load4c(Hp + ((size_t)((ib << 3) + (i >> 7)) << 9) + ((i & 127) << 2));
      }
      waitvm0();
#pragma unroll
      for (int u = 0; u < 4; ++u) {
        const int i = t + (u << 8);
        *(f32x4*)&hs[(i >> 7) * WST + ((i & 127) << 2)] = v[u];
      }
    }
    __syncthreads();

    const int xidx = rev ? (seqlen - 1 - s) : s;
    float xr = 0.f, xz = 0.f, xn = 0.f;
    if (kh == 0) {
      const size_t gxrow = ((size_t)b * seqlen + xidx) * 1536;
      xr = gx[gxrow + col];
      xz = gx[gxrow + 512 + col];
      xn = gx[gxrow + 1024 + col];
    }

    float a0 = 0.f, a1 = 0.f, a2 = 0.f;
#pragma unroll 4
    for (int k4 = 0; k4 < 64; ++k4) {
      const float4 h4 = hsp[k4];
      const float4 x0 = w0[k4];
      const float4 x1 = w1[k4];
      const float4 x2 = w2[k4];
      a0 += x0.x * h4.x + x0.y * h4.y + x0.z * h4.z + x0.w * h4.w;
      a1 += x1.x * h4.x + x1.y * h4.y + x1.z * h4.z + x1.w * h4.w;
      a2 += x2.x * h4.x + x2.y * h4.y + x2.z * h4.z + x2.w * h4.w;
    }
    a0 += __shfl_xor(a0, 1);
    a1 += __shfl_xor(a1, 1);
    a2 += __shfl_xor(a2, 1);

    if (kh == 0) {
      const float hp = hs[item * WST + col];
      const float r = sigm(xr + a0 + bv0);
      const float z = sigm(xz + a1 + bv1);
      const float n = tanhf(xn + r * (a2 + bv2));
      const float hnew = (1.f - z) * n + z * hp;
      float* Hn = (s & 1) ? H0 : H1;
      store1c(Hn + ((size_t)b << 9) + col, hnew);   // coherent write-through
      if (out_seq) out_seq[((size_t)(b * S + xidx) << 9) + col] = hnew;
    }
    if (s + 1 < seqlen) {
      tgt += 32;
      group_barrier_nc(cell, tgt);
    }
  }
}

// Fallback per-step GRU kernel (round-1 proven, grid 192).
__global__ __launch_bounds__(256) void k_gru_step(
    const float* __restrict__ Whh_f, const float* __restrict__ bhh_f,
    const float* __restrict__ Whh_b, const float* __restrict__ bhh_b,
    const float* __restrict__ qWhh,  const float* __restrict__ qbhh,
    const float* __restrict__ gx_f, const float* __restrict__ gx_b,
    const float* __restrict__ gx_q,
    const float* __restrict__ Hf_prev, float* __restrict__ Hf_next,
    const float* __restrict__ Hb_prev, float* __restrict__ Hb_next,
    const float* __restrict__ Hq_prev, float* __restrict__ Hq_next,
    float* __restrict__ facts, float* __restrict__ hb_all, int s) {
  const int bx  = blockIdx.x;
  const int gru = bx >> 6;
  const int ib  = (bx >> 4) & 3;
  const int jb  = bx & 15;
  if (gru == 2 && s >= TQ) return;
  const float* Whh; const float* bhh; const float* gx; const float* Hp; float* Hn;
  int xidx, seqlen;
  if (gru == 0)      { Whh = Whh_f; bhh = bhh_f; gx = gx_f; Hp = Hf_prev; Hn = Hf_next; xidx = s;         seqlen = S;  }
  else if (gru == 1) { Whh = Whh_b; bhh = bhh_b; gx = gx_b; Hp = Hb_prev; Hn = Hb_next; xidx = S - 1 - s; seqlen = S;  }
  else               { Whh = qWhh;  bhh = qbhh;  gx = gx_q; Hp = Hq_prev; Hn = Hq_next; xidx = s;         seqlen = TQ; }
  __shared__ __align__(16) float hs[16][516];
  __shared__ float gd[96][17];
  const int t = threadIdx.x;
  if (s == 0) {
    for (int i = t; i < 16 * 512; i += 256) hs[i >> 9][i & 511] = 0.f;
  } else {
    for (int i = t; i < 16 * 128; i += 256) {
      const int item = i >> 7, c4 = (i & 127) << 2;
      *(float4*)&hs[item][c4] = *(const float4*)(Hp + ((size_t)(ib * 16 + item) << 9) + c4);
    }
  }
  __syncthreads();
  {
    const int item = t & 15;
    const int rw   = t >> 4;
    const float4* wp[6];
#pragma unroll
    for (int rr = 0; rr < 6; ++rr) {
      const int row_local = rw + (rr << 4);
      const int gate = row_local >> 5;
      const int wrow = (gate << 9) + (jb << 5) + (row_local & 31);
      wp[rr] = (const float4*)(Whh + ((size_t)wrow << 9));
    }
    float acc[6] = {};
#pragma unroll 2
    for (int k4 = 0; k4 < 128; ++k4) {
      const float4 h4 = *(const float4*)&hs[item][k4 << 2];
#pragma unroll
      for (int rr = 0; rr < 6; ++rr) {
        const float4 w4 = wp[rr][k4];
        acc[rr] += w4.x * h4.x + w4.y * h4.y + w4.z * h4.z + w4.w * h4.w;
      }
    }
#pragma unroll
    for (int rr = 0; rr < 6; ++rr) gd[rw + (rr << 4)][item] = acc[rr];
  }
  __syncthreads();
  for (int p = t; p < 512; p += 256) {
    const int it2 = p >> 5;
    const int cl  = p & 31;
    const int col = (jb << 5) + cl;
    const int b   = (ib << 4) + it2;
    const size_t gxrow = ((size_t)b * seqlen + xidx) * 1536;
    const float xr = gx[gxrow + col];
    const float xz = gx[gxrow + 512 + col];
    const float xn = gx[gxrow + 1024 + col];
    const float hr = gd[cl][it2]      + bhh[col];
    const float hz = gd[32 + cl][it2] + bhh[512 + col];
    const float hn = gd[64 + cl][it2] + bhh[1024 + col];
    const float hp = hs[it2][col];
    const float r = sigm(xr + hr);
    const float z = sigm(xz + hz);
    const float n = tanhf(xn + r * hn);
    const float hnew = (1.f - z) * n + z * hp;
    Hn[((size_t)b << 9) + col] = hnew;
    if (gru == 0)      facts[((size_t)(b * S + s) << 9) + col]     = hnew;
    else if (gru == 1) hb_all[((size_t)(b * S + xidx) << 9) + col] = hnew;
  }
}

__global__ __launch_bounds__(256) void k_add(float* __restrict__ a, const float* __restrict__ b) {
  const size_t i = (((size_t)blockIdx.x << 8) + threadIdx.x) << 2;
  float4 x = *(float4*)(a + i);
  const float4 y = *(const float4*)(b + i);
  x.x += y.x; x.y += y.y; x.z += y.z; x.w += y.w;
  *(float4*)(a + i) = x;
}

// z (bf16) = [f*q, f*M, |f-q|, |f-M|]
__global__ __launch_bounds__(256) void k_build_z16(const float* __restrict__ facts,
                                                   const float* __restrict__ q,
                                                   const float* __restrict__ M,
                                                   ushort_t* __restrict__ z) {
  const int bs = blockIdx.x;
  const int b  = bs >> 6;
  const int t  = threadIdx.x;
  const size_t zb = (size_t)bs << 11;
  for (int c = t; c < 512; c += 256) {
    const float f  = facts[((size_t)bs << 9) + c];
    const float qv = q[(b << 9) + c];
    const float mv = M[(b << 9) + c];
    z[zb + c]        = f2bf(f * qv);
    z[zb + 512 + c]  = f2bf(f * mv);
    z[zb + 1024 + c] = f2bf(fabsf(f - qv));
    z[zb + 1536 + c] = f2bf(fabsf(f - mv));
  }
}

__global__ __launch_bounds__(256) void k_score_softmax(const float* __restrict__ g1,
                                                       const float* __restrict__ z2w,
                                                       const float* __restrict__ z2b,
                                                       float* __restrict__ G) {
  const int b = blockIdx.x, t = threadIdx.x;
  const int wave = t >> 6, lane = t & 63;
  __shared__ float sc[64];
  for (int si = 0; si < 16; ++si) {
    const int s = wave * 16 + si;
    const float* row = g1 + ((size_t)(b * S + s) << 9) + lane * 8;
    const float* w   = z2w + lane * 8;
    float p = 0.f;
#pragma unroll
    for (int k = 0; k < 8; ++k) p += row[k] * w[k];
#pragma unroll
    for (int off = 32; off; off >>= 1) p += __shfl_xor(p, off);
    if (lane == 0) sc[s] = p + z2b[0];
  }
  __syncthreads();
  if (wave == 0) {
    const float v = sc[lane];
    float m = v;
#pragma unroll
    for (int off = 32; off; off >>= 1) m = fmaxf(m, __shfl_xor(m, off));
    const float e = expf(v - m);
    float su = e;
#pragma unroll
    for (int off = 32; off; off >>= 1) su += __shfl_xor(su, off);
    G[(b << 6) + lane] = e / su;
  }
}

// ---------------------------------------------------------------------------
// Persistent AGRU scan: 256 WGs = 8 ib (8 items) x 32 jb (16 cols).
// Same coherent-exchange + fence-free barrier scheme as k_gru_scan3.
// ---------------------------------------------------------------------------
__global__ __launch_bounds__(256) void k_agru_scan3(
    const float* __restrict__ UrT, const float* __restrict__ UT,
    const float* __restrict__ fRW, const float* __restrict__ fW,
    const float* __restrict__ br, const float* __restrict__ G,
    float* __restrict__ C0, float* __restrict__ C1,
    unsigned* __restrict__ bar) {
  const int ib = blockIdx.x >> 5;
  const int jb = blockIdx.x & 31;
  __shared__ __align__(16) float wlds[32 * WST];
  __shared__ __align__(16) float cs[8 * WST];
  const int t = threadIdx.x;

  for (int i = t; i < 16 * 128; i += 256) {
    const int c = i >> 7, k4 = (i & 127) << 2;
    *(float4*)&wlds[c * WST + k4] =
        *(const float4*)(UrT + (((size_t)((jb << 4) + c)) << 9) + k4);
    *(float4*)&wlds[(16 + c) * WST + k4] =
        *(const float4*)(UT + (((size_t)((jb << 4) + c)) << 9) + k4);
  }

  const int which = t & 1;
  const int cl    = (t >> 1) & 15;
  const int item  = t >> 5;
  const int col   = (jb << 4) + cl;
  const int b     = (ib << 3) + item;
  const float brv = br[col];
  const float4* wp = (const float4*)&wlds[((which << 4) + cl) * WST];
  const float4* csp = (const float4*)&cs[item * WST];
  unsigned* cell = bar + ib * 64;
  unsigned tgt = 0;

  for (int s = 0; s < S; ++s) {
    if (s == 0) {
      for (int i = t; i < 8 * 128; i += 256) {
        const int it = i >> 7, k4 = (i & 127) << 2;
        *(float4*)&cs[it * WST + k4] = float4{0.f, 0.f, 0.f, 0.f};
      }
    } else {
      const float* Cp = (s & 1) ? C1 : C0;
      f32x4 v[4];
#pragma unroll
      for (int u = 0; u < 4; ++u) {
        const int i = t + (u << 8);
        v[u] = load4c(Cp + ((size_t)((ib << 3) + (i >> 7)) << 9) + ((i & 127) << 2));
      }
      waitvm0();
#pragma unroll
      for (int u = 0; u < 4; ++u) {
        const int i = t + (u << 8);
        *(f32x4*)&cs[(i >> 7) * WST + ((i & 127) << 2)] = v[u];
      }
    }
    __syncthreads();

    float fr = 0.f, fw = 0.f, g = 0.f;
    if (which == 0) {
      const size_t fi = ((size_t)(b * S + s) << 9) + col;
      fr = fRW[fi];
      fw = fW[fi];
      g  = G[(b << 6) + s];
    }

    float acc = 0.f;
#pragma unroll 4
    for (int k4 = 0; k4 < 128; ++k4) {
      const float4 c4v = csp[k4];
      const float4 w4 = wp[k4];
      acc += w4.x * c4v.x + w4.y * c4v.y + w4.z * c4v.z + w4.w * c4v.w;
    }
    const float other = __shfl_xor(acc, 1);

    if (which == 0) {
      const float a0 = acc;    // c @ Ur col
      const float a1 = other;  // c @ U col
      const float r  = sigm(fr + a0 + brv);
      const float ht = tanhf(fw + r * a1 + brv);
      const float cp = cs[item * WST + col];
      float* Cn = (s & 1) ? C0 : C1;
      store1c(Cn + ((size_t)b << 9) + col, g * ht + (1.f - g) * cp);
    }
    if (s + 1 < S) {
      tgt += 32;
      group_barrier_nc(cell, tgt);
    }
  }
}

// Fallback per-step AGRU kernel (round-1 proven, grid 128).
__global__ __launch_bounds__(256) void k_agru_step(
    const float* __restrict__ UrT, const float* __restrict__ UT,
    const float* __restrict__ fRW, const float* __restrict__ fW,
    const float* __restrict__ br, const float* __restrict__ G,
    const float* __restrict__ Cprev, float* __restrict__ Cnext, int s) {
  const int ib = blockIdx.x >> 5;
  const int jb = blockIdx.x & 31;
  const int t  = threadIdx.x;
  __shared__ __align__(16) float cs[16][516];
  if (s == 0) {
    for (int i = t; i < 16 * 512; i += 256) cs[i >> 9][i & 511] = 0.f;
  } else {
    for (int i = t; i < 16 * 128; i += 256) {
      const int item = i >> 7, c4 = (i & 127) << 2;
      *(float4*)&cs[item][c4] = *(const float4*)(Cprev + ((size_t)(ib * 16 + item) << 9) + c4);
    }
  }
  __syncthreads();
  const int item = t >> 4;
  const int cl   = t & 15;
  const int col  = (jb << 4) + cl;
  const int b    = (ib << 4) + item;
  const float4* w0 = (const float4*)(UrT + ((size_t)col << 9));
  const float4* w1 = (const float4*)(UT  + ((size_t)col << 9));
  float acc0 = 0.f, acc1 = 0.f;
#pragma unroll 4
  for (int k4 = 0; k4 < 128; ++k4) {
    const float4 c4v = *(const float4*)&cs[item][k4 << 2];
    const float4 a = w0[k4];
    const float4 d = w1[k4];
    acc0 += a.x * c4v.x + a.y * c4v.y + a.z * c4v.z + a.w * c4v.w;
    acc1 += d.x * c4v.x + d.y * c4v.y + d.z * c4v.z + d.w * c4v.w;
  }
  const float g   = G[(b << 6) + s];
  const size_t fi = ((size_t)(b * S + s) << 9) + col;
  const float brv = br[col];
  const float r  = sigm(fRW[fi] + acc0 + brv);
  const float ht = tanhf(fW[fi] + r * acc1 + brv);
  const float cp = cs[item][col];
  Cnext[((size_t)b << 9) + col] = g * ht + (1.f - g) * cp;
}

__global__ __launch_bounds__(256) void k_concat3(const float* __restrict__ M,
                                                 const float* __restrict__ C,
                                                 const float* __restrict__ q,
                                                 float* __restrict__ out) {
  const int b = blockIdx.x, t = threadIdx.x;
  for (int c = t; c < 512; c += 256) {
    out[(size_t)b * 1536 + c]        = M[(b << 9) + c];
    out[(size_t)b * 1536 + 512 + c]  = C[(b << 9) + c];
    out[(size_t)b * 1536 + 1024 + c] = q[(b << 9) + c];
  }
}

__global__ __launch_bounds__(256) void k_concat2(const float* __restrict__ M,
                                                 const float* __restrict__ q,
                                                 float* __restrict__ out) {
  const int b = blockIdx.x, t = threadIdx.x;
  for (int c = t; c < 512; c += 256) {
    out[(size_t)b * 1024 + c]       = M[(b << 9) + c];
    out[(size_t)b * 1024 + 512 + c] = q[(b << 9) + c];
  }
}

}  // namespace

extern "C" void kernel_launch(void* const* d_in, const int* in_sizes, int n_in,
                              void* d_out, int out_size, void* d_ws, size_t ws_size,
                              hipStream_t stream) {
  const int*   contexts  = (const int*)d_in[0];
  const int*   questions = (const int*)d_in[1];
  const float* emb   = (const float*)d_in[2];
  const float* Wih_f = (const float*)d_in[3];
  const float* Whh_f = (const float*)d_in[4];
  const float* bih_f = (const float*)d_in[5];
  const float* bhh_f = (const float*)d_in[6];
  const float* Wih_b = (const float*)d_in[7];
  const float* Whh_b = (const float*)d_in[8];
  const float* bih_b = (const float*)d_in[9];
  const float* bhh_b = (const float*)d_in[10];
  const float* qWih  = (const float*)d_in[11];
  const float* qWhh  = (const float*)d_in[12];
  const float* qbih  = (const float*)d_in[13];
  const float* qbhh  = (const float*)d_in[14];
  const float* Wr    = (const float*)d_in[15];
  const float* Ur    = (const float*)d_in[16];
  const float* br    = (const float*)d_in[17];
  const float* Wm    = (const float*)d_in[18];
  const float* Um    = (const float*)d_in[19];
  const float* z1_w  = (const float*)d_in[20];
  const float* z1_b  = (const float*)d_in[21];
  const float* z2_w  = (const float*)d_in[22];
  const float* z2_b  = (const float*)d_in[23];
  const float* nm_w  = (const float*)d_in[24];
  const float* nm_b  = (const float*)d_in[25];
  const float* ans_w = (const float*)d_in[26];
  const float* ans_b = (const float*)d_in[27];
  (void)in_sizes; (void)n_in; (void)out_size; (void)ws_size;

  float* ws = (float*)d_ws;
  float* WrT      = ws + 0;          // 262144
  float* UrT      = ws + 262144;     // 262144
  float* WT       = ws + 524288;     // 262144
  float* UT       = ws + 786432;     // 262144
  float* facts_in = ws + 1048576;    // 2097152  (reused as fRW)
  float* qe       = ws + 3145728;    // 1048576
  float* gx_f     = ws + 4194304;    // 6291456  (reused as z bf16)
  float* gx_b     = ws + 10485760;   // 6291456
  float* gx_q     = ws + 16777216;   // 3145728  (reused as g1)
  float* facts    = ws + 19922944;   // 2097152
  float* hb       = ws + 22020096;   // 2097152  (reused as fW)
  float* Hbuf     = ws + 24117248;   // 196608
  float* C0       = ws + 24313856;   // 32768
  float* C1       = ws + 24346624;   // 32768
  float* M0       = ws + 24379392;   // 32768
  float* M1       = ws + 24412160;   // 32768
  float* MCq      = ws + 24444928;   // 98304
  float* Mq       = ws + 24543232;   // 65536  (barrier cells live here early)
  float* Gm       = ws + 24608768;   // 4096
  ushort_t* zb16 = (ushort_t*)gx_f;
  float* g1  = gx_q;
  float* fRW = facts_in;
  float* fW  = hb;
  float* preds = (float*)d_out;
  unsigned* bar = (unsigned*)Mq;     // 48 cells x 64 u32 = 12 KB; Mq used only in stage F

  float* Hf[2]  = {Hbuf,          Hbuf + 32768};
  float* Hb2[2] = {Hbuf + 65536,  Hbuf + 98304};
  float* Hq[2]  = {Hbuf + 131072, Hbuf + 163840};
  float* q = Hq[0];
  float* Cb[2] = {C0, C1};

  // ---- barrier cells: zero once per call (monotonic counters) ----
  hipMemsetAsync(bar, 0, 48 * 64 * sizeof(unsigned), stream);

  // ---- stage A: embeddings + weight transposes ----
  k_embed_facts<<<B * S, 256, 0, stream>>>(contexts, emb, facts_in);
  k_embed_q<<<B * TQ, 256, 0, stream>>>(questions, emb, qe);
  dim3 tb(32, 8);
  k_transpose512<<<dim3(16, 16), tb, 0, stream>>>(Wr, WrT);
  k_transpose512<<<dim3(16, 16), tb, 0, stream>>>(Ur, UrT);
  k_transpose512<<<dim3(16, 16), tb, 0, stream>>>(Wm, WT);
  k_transpose512<<<dim3(16, 16), tb, 0, stream>>>(Um, UT);

  // ---- stage B: input-side gate GEMMs (bf16 MFMA, f32 accumulate) ----
  k_gemm_mfma<false, 0><<<dim3(24, 64), 256, 0, stream>>>(facts_in, Wih_f, bih_f, gx_f, 4096, 1536, 512);
  k_gemm_mfma<false, 0><<<dim3(24, 64), 256, 0, stream>>>(facts_in, Wih_b, bih_b, gx_b, 4096, 1536, 512);
  k_gemm_mfma<false, 0><<<dim3(24, 32), 256, 0, stream>>>(qe, qWih, qbih, gx_q, 2048, 1536, 512);

  // ---- stage C: persistent GRU scans (fwd, bwd, question) ----
  {
    bool ok = true;
    {
      int seqlen = S, rev = 0;
      void* a[] = { (void*)&Whh_f, (void*)&bhh_f, (void*)&gx_f, (void*)&Hf[0],
                    (void*)&Hf[1], (void*)&facts, (void*)&seqlen, (void*)&rev,
                    (void*)&bar };
      ok = ok && hipLaunchCooperativeKernel(reinterpret_cast<void*>(k_gru_scan3),
                                            dim3(256), dim3(256), a, 0, stream) == hipSuccess;
    }
    if (ok) {
      int seqlen = S, rev = 1;
      unsigned* bb = bar + 8 * 64;
      void* a[] = { (void*)&Whh_b, (void*)&bhh_b, (void*)&gx_b, (void*)&Hb2[0],
                    (void*)&Hb2[1], (void*)&hb, (void*)&seqlen, (void*)&rev,
                    (void*)&bb };
      ok = hipLaunchCooperativeKernel(reinterpret_cast<void*>(k_gru_scan3),
                                      dim3(256), dim3(256), a, 0, stream) == hipSuccess;
    }
    if (ok) {
      int seqlen = TQ, rev = 0;
      float* nullout = nullptr;
      unsigned* bq = bar + 16 * 64;
      void* a[] = { (void*)&qWhh, (void*)&qbhh, (void*)&gx_q, (void*)&Hq[0],
                    (void*)&Hq[1], (void*)&nullout, (void*)&seqlen, (void*)&rev,
                    (void*)&bq };
      ok = hipLaunchCooperativeKernel(reinterpret_cast<void*>(k_gru_scan3),
                                      dim3(256), dim3(256), a, 0, stream) == hipSuccess;
    }
    if (!ok) {
      for (int s = 0; s < S; ++s)
        k_gru_step<<<192, 256, 0, stream>>>(Whh_f, bhh_f, Whh_b, bhh_b, qWhh, qbhh,
                                            gx_f, gx_b, gx_q,
                                            Hf[s & 1], Hf[(s + 1) & 1],
                                            Hb2[s & 1], Hb2[(s + 1) & 1],
                                            Hq[s & 1], Hq[(s + 1) & 1],
                                            facts, hb, s);
    }
  }
  k_add<<<2048, 256, 0, stream>>>(facts, hb);

  // ---- stage D: hop-invariant precomputes (f32, feeds recurrence) ----
  k_gemm_nt<0><<<dim3(8, 64), 256, 0, stream>>>(facts, WrT, nullptr, fRW, 4096, 512, 512);
  k_gemm_nt<0><<<dim3(8, 64), 256, 0, stream>>>(facts, WT,  nullptr, fW,  4096, 512, 512);

  // ---- stage E: episodic memory hops ----
  const float* Mcur = q;
  for (int h = 0; h < 3; ++h) {
    k_build_z16<<<B * S, 256, 0, stream>>>(facts, q, Mcur, zb16);
    k_gemm_mfma<true, 1><<<dim3(8, 64), 256, 0, stream>>>(zb16, z1_w, z1_b, g1, 4096, 512, 2048);
    k_score_softmax<<<B, 256, 0, stream>>>(g1, z2_w, z2_b, Gm);
    {
      unsigned* ba = bar + (24 + h * 8) * 64;
      void* a[] = { (void*)&UrT, (void*)&UT, (void*)&fRW, (void*)&fW,
                    (void*)&br, (void*)&Gm, (void*)&C0, (void*)&C1, (void*)&ba };
      hipError_t e = hipLaunchCooperativeKernel(reinterpret_cast<void*>(k_agru_scan3),
                                                dim3(256), dim3(256), a, 0, stream);
      if (e != hipSuccess) {
        for (int s = 0; s < S; ++s)
          k_agru_step<<<128, 256, 0, stream>>>(UrT, UT, fRW, fW, br, Gm,
                                               Cb[s & 1], Cb[(s + 1) & 1], s);
      }
    }
    k_concat3<<<B, 256, 0, stream>>>(Mcur, C0, q, MCq);
    float* Mnext = (h & 1) ? M1 : M0;
    k_gemm_nt<2><<<dim3(8, 1), 256, 0, stream>>>(MCq, nm_w, nm_b, Mnext, 64, 512, 1536);
    Mcur = Mnext;
  }

  // ---- stage F: answer projection ----
  k_concat2<<<B, 256, 0, stream>>>(Mcur, q, Mq);
  k_gemm_mfma<false, 0><<<dim3(500, 1), 256, 0, stream>>>(Mq, ans_w, ans_b, preds, 64, 32000, 1024);
}

// Round 6
// 2589.009 us; speedup vs baseline: 3.6460x; 1.2081x over previous
//
#include <hip/hip_runtime.h>
#include <cstddef>
#include <cstdint>

namespace {

constexpr int H  = 512;
constexpr int V  = 32000;
constexpr int B  = 64;
constexpr int S  = 64;
constexpr int T  = 32;
constexpr int TQ = 32;

typedef unsigned short ushort_t;
typedef __attribute__((ext_vector_type(8))) short bf16x8;
typedef __attribute__((ext_vector_type(4))) float f32x4;

__device__ __forceinline__ ushort_t f2bf(float f) {
  union { float f; unsigned u; } v; v.f = f;
  return (ushort_t)((v.u + 0x7FFFu + ((v.u >> 16) & 1u)) >> 16);
}

__device__ __forceinline__ float sigm(float x) { return 1.f / (1.f + expf(-x)); }

// ---- cross-XCD coherent data movement (round-5 proven) ---------------------
__device__ __forceinline__ f32x4 load4c(const float* p) {
  f32x4 v;
  asm volatile("global_load_dwordx4 %0, %1, off sc0 sc1" : "=v"(v) : "v"(p));
  return v;
}
__device__ __forceinline__ void store1c(float* p, float v) {
  asm volatile("global_store_dword %0, %1, off sc0 sc1" :: "v"(p), "v"(v) : "memory");
}
__device__ __forceinline__ void waitvm0() {
  asm volatile("s_waitcnt vmcnt(0)" ::: "memory");
  __builtin_amdgcn_sched_barrier(0);
}

// Group-local barrier, no cache-flushing fences (round-5 proven).
__device__ __forceinline__ void group_barrier_nc(unsigned* cell, unsigned target) {
  waitvm0();
  __syncthreads();
  if (threadIdx.x == 0) {
    __hip_atomic_fetch_add(cell, 1u, __ATOMIC_RELAXED, __HIP_MEMORY_SCOPE_AGENT);
    unsigned v;
    do {
      v = __hip_atomic_load(cell, __ATOMIC_RELAXED, __HIP_MEMORY_SCOPE_AGENT);
      if (v < target) __builtin_amdgcn_s_sleep(2);
    } while (v < target);
  }
  __syncthreads();
}

// ---------------------------------------------------------------------------
// Embedding + positional encoding
// ---------------------------------------------------------------------------
__global__ __launch_bounds__(256) void k_embed_facts(const int* __restrict__ ctx,
                                                     const float* __restrict__ emb,
                                                     float* __restrict__ facts_in) {
  const int bs = blockIdx.x;
  const int s  = bs & (S - 1);
  const int t  = threadIdx.x;
  __shared__ int sidx[T];
  if (t < T) sidx[t] = ctx[(size_t)bs * T + t];
  __syncthreads();
  float a0 = 0.f, a1 = 0.f;
  for (int tt = 0; tt < T; ++tt) {
    const int ix = sidx[tt];
    if (ix != 0) {
      const float* e = emb + ((size_t)ix << 9);
      a0 += e[t];
      a1 += e[t + 256];
    }
  }
  const float sf = (float)s * (1.f / 64.f);
  const float c1 = 1.f - sf;
  const float c2 = (1.f - 2.f * sf) * (1.f / 512.f);
  facts_in[((size_t)bs << 9) + t]       = a0 * (c1 - (float)t * c2);
  facts_in[((size_t)bs << 9) + t + 256] = a1 * (c1 - (float)(t + 256) * c2);
}

__global__ __launch_bounds__(256) void k_embed_q(const int* __restrict__ qidx,
                                                 const float* __restrict__ emb,
                                                 float* __restrict__ qe) {
  const int bt = blockIdx.x;
  const int t  = threadIdx.x;
  const int ix = qidx[bt];
  float v0 = 0.f, v1 = 0.f;
  if (ix != 0) {
    const float* e = emb + ((size_t)ix << 9);
    v0 = e[t];
    v1 = e[t + 256];
  }
  qe[((size_t)bt << 9) + t]       = v0;
  qe[((size_t)bt << 9) + t + 256] = v1;
}

__global__ __launch_bounds__(256) void k_transpose512(const float* __restrict__ src,
                                                      float* __restrict__ dst) {
  __shared__ float tile[32][33];
  const int x0 = blockIdx.x * 32, y0 = blockIdx.y * 32;
  for (int i = threadIdx.y; i < 32; i += 8)
    tile[i][threadIdx.x] = src[(size_t)(y0 + i) * H + x0 + threadIdx.x];
  __syncthreads();
  for (int i = threadIdx.y; i < 32; i += 8)
    dst[(size_t)(x0 + i) * H + y0 + threadIdx.x] = tile[threadIdx.x][i];
}

// ---------------------------------------------------------------------------
// f32 GEMM (NT): C = act(A[M,K] @ B[N,K]^T + bias). 64x64 tile.
// ---------------------------------------------------------------------------
template <int ACT>
__global__ __launch_bounds__(256) void k_gemm_nt(const float* __restrict__ A,
                                                 const float* __restrict__ Bm,
                                                 const float* __restrict__ bias,
                                                 float* __restrict__ C,
                                                 int M, int N, int K) {
  __shared__ __align__(16) float As[32][68];
  __shared__ __align__(16) float Bs[32][68];
  const int t  = threadIdx.x;
  const int tx = t & 15, ty = t >> 4;
  const int m0 = blockIdx.y << 6, n0 = blockIdx.x << 6;
  const int lrow = t >> 3;
  const int lcol = (t & 7) << 2;
  float acc[4][4] = {};
  for (int k0 = 0; k0 < K; k0 += 32) {
    const float4 a0 = *(const float4*)(A  + (size_t)(m0 + lrow) * K      + k0 + lcol);
    const float4 a1 = *(const float4*)(A  + (size_t)(m0 + lrow + 32) * K + k0 + lcol);
    const float4 b0 = *(const float4*)(Bm + (size_t)(n0 + lrow) * K      + k0 + lcol);
    const float4 b1 = *(const float4*)(Bm + (size_t)(n0 + lrow + 32) * K + k0 + lcol);
    __syncthreads();
    As[lcol + 0][lrow] = a0.x; As[lcol + 1][lrow] = a0.y; As[lcol + 2][lrow] = a0.z; As[lcol + 3][lrow] = a0.w;
    As[lcol + 0][lrow + 32] = a1.x; As[lcol + 1][lrow + 32] = a1.y; As[lcol + 2][lrow + 32] = a1.z; As[lcol + 3][lrow + 32] = a1.w;
    Bs[lcol + 0][lrow] = b0.x; Bs[lcol + 1][lrow] = b0.y; Bs[lcol + 2][lrow] = b0.z; Bs[lcol + 3][lrow] = b0.w;
    Bs[lcol + 0][lrow + 32] = b1.x; Bs[lcol + 1][lrow + 32] = b1.y; Bs[lcol + 2][lrow + 32] = b1.z; Bs[lcol + 3][lrow + 32] = b1.w;
    __syncthreads();
#pragma unroll 4
    for (int kk = 0; kk < 32; ++kk) {
      float a[4], b[4];
      *(float4*)a = *(const float4*)&As[kk][ty << 2];
      *(float4*)b = *(const float4*)&Bs[kk][tx << 2];
#pragma unroll
      for (int i = 0; i < 4; ++i)
#pragma unroll
        for (int j = 0; j < 4; ++j) acc[i][j] += a[i] * b[j];
    }
  }
#pragma unroll
  for (int i = 0; i < 4; ++i) {
    const int m = m0 + (ty << 2) + i;
#pragma unroll
    for (int j = 0; j < 4; ++j) {
      const int n = n0 + (tx << 2) + j;
      float v = acc[i][j];
      if (bias) v += bias[n];
      if (ACT == 1) v = tanhf(v);
      if (ACT == 2) v = fmaxf(v, 0.f);
      C[(size_t)m * N + n] = v;
    }
  }
}

// ---------------------------------------------------------------------------
// bf16 MFMA GEMM (NT), validated in round 2.
// ---------------------------------------------------------------------------
template <bool A_BF16, int ACT>
__global__ __launch_bounds__(256) void k_gemm_mfma(const void* __restrict__ Av,
                                                   const float* __restrict__ Bm,
                                                   const float* __restrict__ bias,
                                                   float* __restrict__ C,
                                                   int M, int N, int K) {
  __shared__ __align__(16) ushort_t As[64][72];
  __shared__ __align__(16) ushort_t Bs[64][72];
  const int t    = threadIdx.x;
  const int lane = t & 63;
  const int w    = t >> 6;
  const int wr   = w >> 1, wc = w & 1;
  const int m0 = blockIdx.y << 6, n0 = blockIdx.x << 6;
  const int row = t >> 2;
  const int ch  = t & 3;

  f32x4 acc[2][2] = {};

  for (int k0 = 0; k0 < K; k0 += 64) {
    if (A_BF16) {
      const ushort_t* A16 = (const ushort_t*)Av;
#pragma unroll
      for (int cc = 0; cc < 2; ++cc) {
        const int c8 = ch + cc * 4;
        const uint4 v = *(const uint4*)(A16 + (size_t)(m0 + row) * K + k0 + c8 * 8);
        *(uint4*)&As[row][c8 * 8] = v;
      }
    } else {
      const float* Af = (const float*)Av;
#pragma unroll
      for (int cc = 0; cc < 2; ++cc) {
        const int c8 = ch + cc * 4;
        const float* src = Af + (size_t)(m0 + row) * K + k0 + c8 * 8;
        const float4 f0 = *(const float4*)src;
        const float4 f1 = *(const float4*)(src + 4);
        uint4 v;
        v.x = (unsigned)f2bf(f0.x) | ((unsigned)f2bf(f0.y) << 16);
        v.y = (unsigned)f2bf(f0.z) | ((unsigned)f2bf(f0.w) << 16);
        v.z = (unsigned)f2bf(f1.x) | ((unsigned)f2bf(f1.y) << 16);
        v.w = (unsigned)f2bf(f1.z) | ((unsigned)f2bf(f1.w) << 16);
        *(uint4*)&As[row][c8 * 8] = v;
      }
    }
    {
#pragma unroll
      for (int cc = 0; cc < 2; ++cc) {
        const int c8 = ch + cc * 4;
        const float* src = Bm + (size_t)(n0 + row) * K + k0 + c8 * 8;
        const float4 f0 = *(const float4*)src;
        const float4 f1 = *(const float4*)(src + 4);
        uint4 v;
        v.x = (unsigned)f2bf(f0.x) | ((unsigned)f2bf(f0.y) << 16);
        v.y = (unsigned)f2bf(f0.z) | ((unsigned)f2bf(f0.w) << 16);
        v.z = (unsigned)f2bf(f1.x) | ((unsigned)f2bf(f1.y) << 16);
        v.w = (unsigned)f2bf(f1.z) | ((unsigned)f2bf(f1.w) << 16);
        *(uint4*)&Bs[row][c8 * 8] = v;
      }
    }
    __syncthreads();
#pragma unroll
    for (int ks = 0; ks < 2; ++ks) {
      bf16x8 a[2], b[2];
#pragma unroll
      for (int fr = 0; fr < 2; ++fr)
        a[fr] = *(const bf16x8*)&As[wr * 32 + fr * 16 + (lane & 15)][ks * 32 + (lane >> 4) * 8];
#pragma unroll
      for (int fc = 0; fc < 2; ++fc)
        b[fc] = *(const bf16x8*)&Bs[wc * 32 + fc * 16 + (lane & 15)][ks * 32 + (lane >> 4) * 8];
#pragma unroll
      for (int fr = 0; fr < 2; ++fr)
#pragma unroll
        for (int fc = 0; fc < 2; ++fc)
          acc[fr][fc] = __builtin_amdgcn_mfma_f32_16x16x32_bf16(a[fr], b[fc], acc[fr][fc], 0, 0, 0);
    }
    __syncthreads();
  }
#pragma unroll
  for (int fr = 0; fr < 2; ++fr) {
#pragma unroll
    for (int fc = 0; fc < 2; ++fc) {
      const int rbase = m0 + wr * 32 + fr * 16 + ((lane >> 4) << 2);
      const int col   = n0 + wc * 32 + fc * 16 + (lane & 15);
      const float bv  = bias ? bias[col] : 0.f;
#pragma unroll
      for (int j = 0; j < 4; ++j) {
        float v = acc[fr][fc][j] + bv;
        if (ACT == 1) v = tanhf(v);
        if (ACT == 2) v = fmaxf(v, 0.f);
        C[(size_t)(rbase + j) * N + col] = v;
      }
    }
  }
}

// ---------------------------------------------------------------------------
// Merged persistent GRU scan (all 3 GRUs): 768 WGs = 3 gru x 8 ib x 32 jb.
// Weights in VGPRs (96/thread); LDS carries only h (broadcast reads) +
// a 6KB reduction buffer. 3 WGs/CU co-resident so barrier latency of one
// group hides under other groups' compute.
// Thread map: cl = t&15 (col), kq = t>>4 (k-slice, interleaved j*64+kq*4).
// ---------------------------------------------------------------------------
__global__ __launch_bounds__(256, 3) void k_gru_scan_mg(
    const float* __restrict__ Whh_f, const float* __restrict__ bhh_f,
    const float* __restrict__ Whh_b, const float* __restrict__ bhh_b,
    const float* __restrict__ qWhh,  const float* __restrict__ qbhh,
    const float* __restrict__ gx_f, const float* __restrict__ gx_b,
    const float* __restrict__ gx_q,
    float* __restrict__ Hbuf, float* __restrict__ facts,
    float* __restrict__ hb_all, unsigned* __restrict__ bar) {
  const int bx  = blockIdx.x;
  const int gru = bx >> 8;
  const int ib  = (bx >> 5) & 7;
  const int jb  = bx & 31;
  const float* Whh; const float* bhh; const float* gx;
  float* H0; float* H1; float* out_seq; int seqlen, rev;
  if (gru == 0)      { Whh = Whh_f; bhh = bhh_f; gx = gx_f; H0 = Hbuf;          H1 = Hbuf + 32768;  out_seq = facts;   seqlen = S;  rev = 0; }
  else if (gru == 1) { Whh = Whh_b; bhh = bhh_b; gx = gx_b; H0 = Hbuf + 65536;  H1 = Hbuf + 98304;  out_seq = hb_all;  seqlen = S;  rev = 1; }
  else               { Whh = qWhh;  bhh = qbhh;  gx = gx_q; H0 = Hbuf + 131072; H1 = Hbuf + 163840; out_seq = nullptr; seqlen = TQ; rev = 0; }

  __shared__ __align__(16) float hs[8 * 512];        // 16 KB, full h for 8 items
  __shared__ float red[4 * 8 * 3 * 16];              // 6 KB kq-reduction buffer
  const int t  = threadIdx.x;
  const int cl = t & 15;
  const int kq = t >> 4;

  // ---- weight slice -> VGPRs (once): rows g*512 + jb*16 + cl, k = j*64+kq*4
  f32x4 wv[3][8];
#pragma unroll
  for (int g = 0; g < 3; ++g) {
    const float* wrow = Whh + ((size_t)(g * 512 + (jb << 4) + cl) << 9) + (kq << 2);
#pragma unroll
    for (int j = 0; j < 8; ++j) wv[g][j] = *(const f32x4*)(wrow + j * 64);
  }

  const int col = (jb << 4) + cl;
  const float bv0 = bhh[col], bv1 = bhh[512 + col], bv2 = bhh[1024 + col];
  unsigned* cell = bar + (bx >> 5) * 64;
  unsigned tgt = 0;

  for (int s = 0; s < seqlen; ++s) {
    // ---- stage h (all 512 cols x 8 items) into LDS ----
    if (s == 0) {
      for (int i = t; i < 8 * 128; i += 256)
        *(f32x4*)&hs[(i >> 7) * 512 + ((i & 127) << 2)] = f32x4{0.f, 0.f, 0.f, 0.f};
    } else {
      const float* Hp = (s & 1) ? H1 : H0;
      f32x4 v[4];
#pragma unroll
      for (int u = 0; u < 4; ++u) {
        const int i = t + (u << 8);
        v[u] = load4c(Hp + ((size_t)((ib << 3) + (i >> 7)) << 9) + ((i & 127) << 2));
      }
      waitvm0();
#pragma unroll
      for (int u = 0; u < 4; ++u) {
        const int i = t + (u << 8);
        *(f32x4*)&hs[(i >> 7) * 512 + ((i & 127) << 2)] = v[u];
      }
    }
    __syncthreads();

    // ---- gate dots: weights from VGPR, h broadcast from LDS ----
    float acc[8][3] = {};
#pragma unroll
    for (int it = 0; it < 8; ++it) {
      const float* hrow = &hs[it * 512 + (kq << 2)];
#pragma unroll
      for (int j = 0; j < 8; ++j) {
        const f32x4 h4 = *(const f32x4*)(hrow + j * 64);
#pragma unroll
        for (int g = 0; g < 3; ++g)
          acc[it][g] += wv[g][j].x * h4.x + wv[g][j].y * h4.y +
                        wv[g][j].z * h4.z + wv[g][j].w * h4.w;
      }
    }
    // ---- reduce over kq: intra-wave (4 kq) then LDS across 4 waves ----
#pragma unroll
    for (int it = 0; it < 8; ++it)
#pragma unroll
      for (int g = 0; g < 3; ++g) {
        acc[it][g] += __shfl_xor(acc[it][g], 16);
        acc[it][g] += __shfl_xor(acc[it][g], 32);
      }
    {
      const int wv2 = t >> 6;
      if ((t & 48) == 0) {
#pragma unroll
        for (int it = 0; it < 8; ++it)
#pragma unroll
          for (int g = 0; g < 3; ++g)
            red[((wv2 * 8 + it) * 3 + g) * 16 + cl] = acc[it][g];
      }
    }
    __syncthreads();

    // ---- phase 2: 128 threads finalize (item, col) ----
    if (t < 128) {
      const int it = t >> 4;
      const int b  = (ib << 3) + it;
      float hr = 0.f, hz = 0.f, hn = 0.f;
#pragma unroll
      for (int w2 = 0; w2 < 4; ++w2) {
        hr += red[((w2 * 8 + it) * 3 + 0) * 16 + cl];
        hz += red[((w2 * 8 + it) * 3 + 1) * 16 + cl];
        hn += red[((w2 * 8 + it) * 3 + 2) * 16 + cl];
      }
      const int xidx = rev ? (seqlen - 1 - s) : s;
      const size_t gxrow = ((size_t)b * seqlen + xidx) * 1536;
      const float xr = gx[gxrow + col];
      const float xz = gx[gxrow + 512 + col];
      const float xn = gx[gxrow + 1024 + col];
      const float hp = hs[it * 512 + col];
      const float r = sigm(xr + hr + bv0);
      const float z = sigm(xz + hz + bv1);
      const float n = tanhf(xn + r * (hn + bv2));
      const float hnew = (1.f - z) * n + z * hp;
      float* Hn = (s & 1) ? H0 : H1;
      store1c(Hn + ((size_t)b << 9) + col, hnew);
      if (out_seq) out_seq[((size_t)(b * S + xidx) << 9) + col] = hnew;
    }
    if (s + 1 < seqlen) {
      tgt += 32;
      group_barrier_nc(cell, tgt);
    }
  }
}

// Fallback per-step GRU kernel (round-1 proven, grid 192).
__global__ __launch_bounds__(256) void k_gru_step(
    const float* __restrict__ Whh_f, const float* __restrict__ bhh_f,
    const float* __restrict__ Whh_b, const float* __restrict__ bhh_b,
    const float* __restrict__ qWhh,  const float* __restrict__ qbhh,
    const float* __restrict__ gx_f, const float* __restrict__ gx_b,
    const float* __restrict__ gx_q,
    const float* __restrict__ Hf_prev, float* __restrict__ Hf_next,
    const float* __restrict__ Hb_prev, float* __restrict__ Hb_next,
    const float* __restrict__ Hq_prev, float* __restrict__ Hq_next,
    float* __restrict__ facts, float* __restrict__ hb_all, int s) {
  const int bx  = blockIdx.x;
  const int gru = bx >> 6;
  const int ib  = (bx >> 4) & 3;
  const int jb  = bx & 15;
  if (gru == 2 && s >= TQ) return;
  const float* Whh; const float* bhh; const float* gx; const float* Hp; float* Hn;
  int xidx, seqlen;
  if (gru == 0)      { Whh = Whh_f; bhh = bhh_f; gx = gx_f; Hp = Hf_prev; Hn = Hf_next; xidx = s;         seqlen = S;  }
  else if (gru == 1) { Whh = Whh_b; bhh = bhh_b; gx = gx_b; Hp = Hb_prev; Hn = Hb_next; xidx = S - 1 - s; seqlen = S;  }
  else               { Whh = qWhh;  bhh = qbhh;  gx = gx_q; Hp = Hq_prev; Hn = Hq_next; xidx = s;         seqlen = TQ; }
  __shared__ __align__(16) float hs[16][516];
  __shared__ float gd[96][17];
  const int t = threadIdx.x;
  if (s == 0) {
    for (int i = t; i < 16 * 512; i += 256) hs[i >> 9][i & 511] = 0.f;
  } else {
    for (int i = t; i < 16 * 128; i += 256) {
      const int item = i >> 7, c4 = (i & 127) << 2;
      *(float4*)&hs[item][c4] = *(const float4*)(Hp + ((size_t)(ib * 16 + item) << 9) + c4);
    }
  }
  __syncthreads();
  {
    const int item = t & 15;
    const int rw   = t >> 4;
    const float4* wp[6];
#pragma unroll
    for (int rr = 0; rr < 6; ++rr) {
      const int row_local = rw + (rr << 4);
      const int gate = row_local >> 5;
      const int wrow = (gate << 9) + (jb << 5) + (row_local & 31);
      wp[rr] = (const float4*)(Whh + ((size_t)wrow << 9));
    }
    float acc[6] = {};
#pragma unroll 2
    for (int k4 = 0; k4 < 128; ++k4) {
      const float4 h4 = *(const float4*)&hs[item][k4 << 2];
#pragma unroll
      for (int rr = 0; rr < 6; ++rr) {
        const float4 w4 = wp[rr][k4];
        acc[rr] += w4.x * h4.x + w4.y * h4.y + w4.z * h4.z + w4.w * h4.w;
      }
    }
#pragma unroll
    for (int rr = 0; rr < 6; ++rr) gd[rw + (rr << 4)][item] = acc[rr];
  }
  __syncthreads();
  for (int p = t; p < 512; p += 256) {
    const int it2 = p >> 5;
    const int cl  = p & 31;
    const int col = (jb << 5) + cl;
    const int b   = (ib << 4) + it2;
    const size_t gxrow = ((size_t)b * seqlen + xidx) * 1536;
    const float xr = gx[gxrow + col];
    const float xz = gx[gxrow + 512 + col];
    const float xn = gx[gxrow + 1024 + col];
    const float hr = gd[cl][it2]      + bhh[col];
    const float hz = gd[32 + cl][it2] + bhh[512 + col];
    const float hn = gd[64 + cl][it2] + bhh[1024 + col];
    const float hp = hs[it2][col];
    const float r = sigm(xr + hr);
    const float z = sigm(xz + hz);
    const float n = tanhf(xn + r * hn);
    const float hnew = (1.f - z) * n + z * hp;
    Hn[((size_t)b << 9) + col] = hnew;
    if (gru == 0)      facts[((size_t)(b * S + s) << 9) + col]     = hnew;
    else if (gru == 1) hb_all[((size_t)(b * S + xidx) << 9) + col] = hnew;
  }
}

__global__ __launch_bounds__(256) void k_add(float* __restrict__ a, const float* __restrict__ b) {
  const size_t i = (((size_t)blockIdx.x << 8) + threadIdx.x) << 2;
  float4 x = *(float4*)(a + i);
  const float4 y = *(const float4*)(b + i);
  x.x += y.x; x.y += y.y; x.z += y.z; x.w += y.w;
  *(float4*)(a + i) = x;
}

// z (bf16) = [f*q, f*M, |f-q|, |f-M|]
__global__ __launch_bounds__(256) void k_build_z16(const float* __restrict__ facts,
                                                   const float* __restrict__ q,
                                                   const float* __restrict__ M,
                                                   ushort_t* __restrict__ z) {
  const int bs = blockIdx.x;
  const int b  = bs >> 6;
  const int t  = threadIdx.x;
  const size_t zb = (size_t)bs << 11;
  for (int c = t; c < 512; c += 256) {
    const float f  = facts[((size_t)bs << 9) + c];
    const float qv = q[(b << 9) + c];
    const float mv = M[(b << 9) + c];
    z[zb + c]        = f2bf(f * qv);
    z[zb + 512 + c]  = f2bf(f * mv);
    z[zb + 1024 + c] = f2bf(fabsf(f - qv));
    z[zb + 1536 + c] = f2bf(fabsf(f - mv));
  }
}

__global__ __launch_bounds__(256) void k_score_softmax(const float* __restrict__ g1,
                                                       const float* __restrict__ z2w,
                                                       const float* __restrict__ z2b,
                                                       float* __restrict__ G) {
  const int b = blockIdx.x, t = threadIdx.x;
  const int wave = t >> 6, lane = t & 63;
  __shared__ float sc[64];
  for (int si = 0; si < 16; ++si) {
    const int s = wave * 16 + si;
    const float* row = g1 + ((size_t)(b * S + s) << 9) + lane * 8;
    const float* w   = z2w + lane * 8;
    float p = 0.f;
#pragma unroll
    for (int k = 0; k < 8; ++k) p += row[k] * w[k];
#pragma unroll
    for (int off = 32; off; off >>= 1) p += __shfl_xor(p, off);
    if (lane == 0) sc[s] = p + z2b[0];
  }
  __syncthreads();
  if (wave == 0) {
    const float v = sc[lane];
    float m = v;
#pragma unroll
    for (int off = 32; off; off >>= 1) m = fmaxf(m, __shfl_xor(m, off));
    const float e = expf(v - m);
    float su = e;
#pragma unroll
    for (int off = 32; off; off >>= 1) su += __shfl_xor(su, off);
    G[(b << 6) + lane] = e / su;
  }
}

// ---------------------------------------------------------------------------
// Persistent AGRU scan v2: 256 WGs = 8 ib x 32 jb; Ur/U column slices in
// VGPRs (64/thread); same broadcast-LDS + reduction structure as GRU merge.
// ---------------------------------------------------------------------------
__global__ __launch_bounds__(256) void k_agru_scan_v2(
    const float* __restrict__ UrT, const float* __restrict__ UT,
    const float* __restrict__ fRW, const float* __restrict__ fW,
    const float* __restrict__ br, const float* __restrict__ G,
    float* __restrict__ C0, float* __restrict__ C1,
    unsigned* __restrict__ bar) {
  const int ib = blockIdx.x >> 5;
  const int jb = blockIdx.x & 31;
  __shared__ __align__(16) float cs[8 * 512];
  __shared__ float red[4 * 8 * 2 * 16];
  const int t  = threadIdx.x;
  const int cl = t & 15;
  const int kq = t >> 4;

  f32x4 wr[8], wu[8];
  {
    const float* r0 = UrT + ((size_t)((jb << 4) + cl) << 9) + (kq << 2);
    const float* r1 = UT  + ((size_t)((jb << 4) + cl) << 9) + (kq << 2);
#pragma unroll
    for (int j = 0; j < 8; ++j) {
      wr[j] = *(const f32x4*)(r0 + j * 64);
      wu[j] = *(const f32x4*)(r1 + j * 64);
    }
  }

  const int col = (jb << 4) + cl;
  const float brv = br[col];
  unsigned* cell = bar + ib * 64;
  unsigned tgt = 0;

  for (int s = 0; s < S; ++s) {
    if (s == 0) {
      for (int i = t; i < 8 * 128; i += 256)
        *(f32x4*)&cs[(i >> 7) * 512 + ((i & 127) << 2)] = f32x4{0.f, 0.f, 0.f, 0.f};
    } else {
      const float* Cp = (s & 1) ? C1 : C0;
      f32x4 v[4];
#pragma unroll
      for (int u = 0; u < 4; ++u) {
        const int i = t + (u << 8);
        v[u] = load4c(Cp + ((size_t)((ib << 3) + (i >> 7)) << 9) + ((i & 127) << 2));
      }
      waitvm0();
#pragma unroll
      for (int u = 0; u < 4; ++u) {
        const int i = t + (u << 8);
        *(f32x4*)&cs[(i >> 7) * 512 + ((i & 127) << 2)] = v[u];
      }
    }
    __syncthreads();

    float acc[8][2] = {};
#pragma unroll
    for (int it = 0; it < 8; ++it) {
      const float* crow = &cs[it * 512 + (kq << 2)];
#pragma unroll
      for (int j = 0; j < 8; ++j) {
        const f32x4 c4 = *(const f32x4*)(crow + j * 64);
        acc[it][0] += wr[j].x * c4.x + wr[j].y * c4.y + wr[j].z * c4.z + wr[j].w * c4.w;
        acc[it][1] += wu[j].x * c4.x + wu[j].y * c4.y + wu[j].z * c4.z + wu[j].w * c4.w;
      }
    }
#pragma unroll
    for (int it = 0; it < 8; ++it)
#pragma unroll
      for (int g = 0; g < 2; ++g) {
        acc[it][g] += __shfl_xor(acc[it][g], 16);
        acc[it][g] += __shfl_xor(acc[it][g], 32);
      }
    {
      const int wv2 = t >> 6;
      if ((t & 48) == 0) {
#pragma unroll
        for (int it = 0; it < 8; ++it) {
          red[((wv2 * 8 + it) * 2 + 0) * 16 + cl] = acc[it][0];
          red[((wv2 * 8 + it) * 2 + 1) * 16 + cl] = acc[it][1];
        }
      }
    }
    __syncthreads();

    if (t < 128) {
      const int it = t >> 4;
      const int b  = (ib << 3) + it;
      float a0 = 0.f, a1 = 0.f;
#pragma unroll
      for (int w2 = 0; w2 < 4; ++w2) {
        a0 += red[((w2 * 8 + it) * 2 + 0) * 16 + cl];
        a1 += red[((w2 * 8 + it) * 2 + 1) * 16 + cl];
      }
      const float g   = G[(b << 6) + s];
      const size_t fi = ((size_t)(b * S + s) << 9) + col;
      const float r  = sigm(fRW[fi] + a0 + brv);
      const float ht = tanhf(fW[fi] + r * a1 + brv);
      const float cp = cs[it * 512 + col];
      float* Cn = (s & 1) ? C0 : C1;
      store1c(Cn + ((size_t)b << 9) + col, g * ht + (1.f - g) * cp);
    }
    if (s + 1 < S) {
      tgt += 32;
      group_barrier_nc(cell, tgt);
    }
  }
}

// Fallback per-step AGRU kernel (round-1 proven, grid 128).
__global__ __launch_bounds__(256) void k_agru_step(
    const float* __restrict__ UrT, const float* __restrict__ UT,
    const float* __restrict__ fRW, const float* __restrict__ fW,
    const float* __restrict__ br, const float* __restrict__ G,
    const float* __restrict__ Cprev, float* __restrict__ Cnext, int s) {
  const int ib = blockIdx.x >> 5;
  const int jb = blockIdx.x & 31;
  const int t  = threadIdx.x;
  __shared__ __align__(16) float cs[16][516];
  if (s == 0) {
    for (int i = t; i < 16 * 512; i += 256) cs[i >> 9][i & 511] = 0.f;
  } else {
    for (int i = t; i < 16 * 128; i += 256) {
      const int item = i >> 7, c4 = (i & 127) << 2;
      *(float4*)&cs[item][c4] = *(const float4*)(Cprev + ((size_t)(ib * 16 + item) << 9) + c4);
    }
  }
  __syncthreads();
  const int item = t >> 4;
  const int cl   = t & 15;
  const int col  = (jb << 4) + cl;
  const int b    = (ib << 4) + item;
  const float4* w0 = (const float4*)(UrT + ((size_t)col << 9));
  const float4* w1 = (const float4*)(UT  + ((size_t)col << 9));
  float acc0 = 0.f, acc1 = 0.f;
#pragma unroll 4
  for (int k4 = 0; k4 < 128; ++k4) {
    const float4 c4v = *(const float4*)&cs[item][k4 << 2];
    const float4 a = w0[k4];
    const float4 d = w1[k4];
    acc0 += a.x * c4v.x + a.y * c4v.y + a.z * c4v.z + a.w * c4v.w;
    acc1 += d.x * c4v.x + d.y * c4v.y + d.z * c4v.z + d.w * c4v.w;
  }
  const float g   = G[(b << 6) + s];
  const size_t fi = ((size_t)(b * S + s) << 9) + col;
  const float brv = br[col];
  const float r  = sigm(fRW[fi] + acc0 + brv);
  const float ht = tanhf(fW[fi] + r * acc1 + brv);
  const float cp = cs[item][col];
  Cnext[((size_t)b << 9) + col] = g * ht + (1.f - g) * cp;
}

__global__ __launch_bounds__(256) void k_concat3(const float* __restrict__ M,
                                                 const float* __restrict__ C,
                                                 const float* __restrict__ q,
                                                 float* __restrict__ out) {
  const int b = blockIdx.x, t = threadIdx.x;
  for (int c = t; c < 512; c += 256) {
    out[(size_t)b * 1536 + c]        = M[(b << 9) + c];
    out[(size_t)b * 1536 + 512 + c]  = C[(b << 9) + c];
    out[(size_t)b * 1536 + 1024 + c] = q[(b << 9) + c];
  }
}

__global__ __launch_bounds__(256) void k_concat2(const float* __restrict__ M,
                                                 const float* __restrict__ q,
                                                 float* __restrict__ out) {
  const int b = blockIdx.x, t = threadIdx.x;
  for (int c = t; c < 512; c += 256) {
    out[(size_t)b * 1024 + c]       = M[(b << 9) + c];
    out[(size_t)b * 1024 + 512 + c] = q[(b << 9) + c];
  }
}

}  // namespace

extern "C" void kernel_launch(void* const* d_in, const int* in_sizes, int n_in,
                              void* d_out, int out_size, void* d_ws, size_t ws_size,
                              hipStream_t stream) {
  const int*   contexts  = (const int*)d_in[0];
  const int*   questions = (const int*)d_in[1];
  const float* emb   = (const float*)d_in[2];
  const float* Wih_f = (const float*)d_in[3];
  const float* Whh_f = (const float*)d_in[4];
  const float* bih_f = (const float*)d_in[5];
  const float* bhh_f = (const float*)d_in[6];
  const float* Wih_b = (const float*)d_in[7];
  const float* Whh_b = (const float*)d_in[8];
  const float* bih_b = (const float*)d_in[9];
  const float* bhh_b = (const float*)d_in[10];
  const float* qWih  = (const float*)d_in[11];
  const float* qWhh  = (const float*)d_in[12];
  const float* qbih  = (const float*)d_in[13];
  const float* qbhh  = (const float*)d_in[14];
  const float* Wr    = (const float*)d_in[15];
  const float* Ur    = (const float*)d_in[16];
  const float* br    = (const float*)d_in[17];
  const float* Wm    = (const float*)d_in[18];
  const float* Um    = (const float*)d_in[19];
  const float* z1_w  = (const float*)d_in[20];
  const float* z1_b  = (const float*)d_in[21];
  const float* z2_w  = (const float*)d_in[22];
  const float* z2_b  = (const float*)d_in[23];
  const float* nm_w  = (const float*)d_in[24];
  const float* nm_b  = (const float*)d_in[25];
  const float* ans_w = (const float*)d_in[26];
  const float* ans_b = (const float*)d_in[27];
  (void)in_sizes; (void)n_in; (void)out_size; (void)ws_size;

  float* ws = (float*)d_ws;
  float* WrT      = ws + 0;          // 262144
  float* UrT      = ws + 262144;     // 262144
  float* WT       = ws + 524288;     // 262144
  float* UT       = ws + 786432;     // 262144
  float* facts_in = ws + 1048576;    // 2097152  (reused as fRW)
  float* qe       = ws + 3145728;    // 1048576
  float* gx_f     = ws + 4194304;    // 6291456  (reused as z bf16)
  float* gx_b     = ws + 10485760;   // 6291456
  float* gx_q     = ws + 16777216;   // 3145728  (reused as g1)
  float* facts    = ws + 19922944;   // 2097152
  float* hb       = ws + 22020096;   // 2097152  (reused as fW)
  float* Hbuf     = ws + 24117248;   // 196608
  float* C0       = ws + 24313856;   // 32768
  float* C1       = ws + 24346624;   // 32768
  float* M0       = ws + 24379392;   // 32768
  float* M1       = ws + 24412160;   // 32768
  float* MCq      = ws + 24444928;   // 98304
  float* Mq       = ws + 24543232;   // 65536  (barrier cells live here early)
  float* Gm       = ws + 24608768;   // 4096
  ushort_t* zb16 = (ushort_t*)gx_f;
  float* g1  = gx_q;
  float* fRW = facts_in;
  float* fW  = hb;
  float* preds = (float*)d_out;
  unsigned* bar = (unsigned*)Mq;     // 48 cells x 64 u32; Mq used only in stage F

  float* Hf[2]  = {Hbuf,          Hbuf + 32768};
  float* Hb2[2] = {Hbuf + 65536,  Hbuf + 98304};
  float* Hq[2]  = {Hbuf + 131072, Hbuf + 163840};
  float* q = Hq[0];
  float* Cb[2] = {C0, C1};

  // ---- barrier cells: zero once per call (monotonic counters) ----
  hipMemsetAsync(bar, 0, 48 * 64 * sizeof(unsigned), stream);

  // ---- stage A: embeddings + weight transposes ----
  k_embed_facts<<<B * S, 256, 0, stream>>>(contexts, emb, facts_in);
  k_embed_q<<<B * TQ, 256, 0, stream>>>(questions, emb, qe);
  dim3 tb(32, 8);
  k_transpose512<<<dim3(16, 16), tb, 0, stream>>>(Wr, WrT);
  k_transpose512<<<dim3(16, 16), tb, 0, stream>>>(Ur, UrT);
  k_transpose512<<<dim3(16, 16), tb, 0, stream>>>(Wm, WT);
  k_transpose512<<<dim3(16, 16), tb, 0, stream>>>(Um, UT);

  // ---- stage B: input-side gate GEMMs (bf16 MFMA, f32 accumulate) ----
  k_gemm_mfma<false, 0><<<dim3(24, 64), 256, 0, stream>>>(facts_in, Wih_f, bih_f, gx_f, 4096, 1536, 512);
  k_gemm_mfma<false, 0><<<dim3(24, 64), 256, 0, stream>>>(facts_in, Wih_b, bih_b, gx_b, 4096, 1536, 512);
  k_gemm_mfma<false, 0><<<dim3(24, 32), 256, 0, stream>>>(qe, qWih, qbih, gx_q, 2048, 1536, 512);

  // ---- stage C: merged persistent GRU scans (fwd + bwd + question) ----
  {
    void* a[] = { (void*)&Whh_f, (void*)&bhh_f, (void*)&Whh_b, (void*)&bhh_b,
                  (void*)&qWhh, (void*)&qbhh, (void*)&gx_f, (void*)&gx_b,
                  (void*)&gx_q, (void*)&Hbuf, (void*)&facts, (void*)&hb,
                  (void*)&bar };
    hipError_t e = hipLaunchCooperativeKernel(reinterpret_cast<void*>(k_gru_scan_mg),
                                              dim3(768), dim3(256), a, 0, stream);
    if (e != hipSuccess) {
      for (int s = 0; s < S; ++s)
        k_gru_step<<<192, 256, 0, stream>>>(Whh_f, bhh_f, Whh_b, bhh_b, qWhh, qbhh,
                                            gx_f, gx_b, gx_q,
                                            Hf[s & 1], Hf[(s + 1) & 1],
                                            Hb2[s & 1], Hb2[(s + 1) & 1],
                                            Hq[s & 1], Hq[(s + 1) & 1],
                                            facts, hb, s);
    }
  }
  k_add<<<2048, 256, 0, stream>>>(facts, hb);

  // ---- stage D: hop-invariant precomputes (f32, isolate this round) ----
  k_gemm_nt<0><<<dim3(8, 64), 256, 0, stream>>>(facts, WrT, nullptr, fRW, 4096, 512, 512);
  k_gemm_nt<0><<<dim3(8, 64), 256, 0, stream>>>(facts, WT,  nullptr, fW,  4096, 512, 512);

  // ---- stage E: episodic memory hops ----
  const float* Mcur = q;
  for (int h = 0; h < 3; ++h) {
    k_build_z16<<<B * S, 256, 0, stream>>>(facts, q, Mcur, zb16);
    k_gemm_mfma<true, 1><<<dim3(8, 64), 256, 0, stream>>>(zb16, z1_w, z1_b, g1, 4096, 512, 2048);
    k_score_softmax<<<B, 256, 0, stream>>>(g1, z2_w, z2_b, Gm);
    {
      unsigned* ba = bar + (24 + h * 8) * 64;
      void* a[] = { (void*)&UrT, (void*)&UT, (void*)&fRW, (void*)&fW,
                    (void*)&br, (void*)&Gm, (void*)&C0, (void*)&C1, (void*)&ba };
      hipError_t e = hipLaunchCooperativeKernel(reinterpret_cast<void*>(k_agru_scan_v2),
                                                dim3(256), dim3(256), a, 0, stream);
      if (e != hipSuccess) {
        for (int s = 0; s < S; ++s)
          k_agru_step<<<128, 256, 0, stream>>>(UrT, UT, fRW, fW, br, Gm,
                                               Cb[s & 1], Cb[(s + 1) & 1], s);
      }
    }
    k_concat3<<<B, 256, 0, stream>>>(Mcur, C0, q, MCq);
    float* Mnext = (h & 1) ? M1 : M0;
    k_gemm_nt<2><<<dim3(8, 1), 256, 0, stream>>>(MCq, nm_w, nm_b, Mnext, 64, 512, 1536);
    Mcur = Mnext;
  }

  // ---- stage F: answer projection ----
  k_concat2<<<B, 256, 0, stream>>>(Mcur, q, Mq);
  k_gemm_mfma<false, 0><<<dim3(500, 1), 256, 0, stream>>>(Mq, ans_w, ans_b, preds, 64, 32000, 1024);
}